// Round 3
// baseline (10859.188 us; speedup 1.0000x reference)
//
#include <hip/hip_runtime.h>
#include <hip/hip_bf16.h>
#include <math.h>

#define HH 384
#define WW 384
#define HW (HH*WW)
#define WP 386              // padded row stride (1-px guard ring)
#define PP (386*386)        // padded image pixels
#define BB 4
#define CC 8
#define NLAYERS 5
#define CGITERS 10
#define PI_F 3.14159265358979323846f

typedef __attribute__((ext_vector_type(8))) short short8;
typedef __attribute__((ext_vector_type(4))) float floatx4;

struct cf { float x, y; };
__device__ __forceinline__ cf cadd(cf a, cf b){ cf r; r.x=a.x+b.x; r.y=a.y+b.y; return r; }
__device__ __forceinline__ cf csub(cf a, cf b){ cf r; r.x=a.x-b.x; r.y=a.y-b.y; return r; }
__device__ __forceinline__ cf cmul(cf a, cf b){ cf r; r.x=a.x*b.x - a.y*b.y; r.y=a.x*b.y + a.y*b.x; return r; }
__device__ __forceinline__ cf csqr(cf a){ cf r; r.x = a.x*a.x - a.y*a.y; r.y = 2.f*a.x*a.y; return r; }
__device__ __forceinline__ cf shflxor(cf v, int m){ cf r; r.x = __shfl_xor(v.x, m); r.y = __shfl_xor(v.y, m); return r; }
__device__ __forceinline__ int brev7(int l){ return (int)(__brev((unsigned)l) >> 25); }
__device__ __forceinline__ int padi(int i){ return i + (i >> 3); }

__device__ __forceinline__ void radix3(cf a0, cf a1, cf a2, float s3, cf y[3]) {
  float tx = a1.x + a2.x, ty_ = a1.y + a2.y;
  float ux = a1.x - a2.x, uy = a1.y - a2.y;
  y[0].x = a0.x + tx;              y[0].y = a0.y + ty_;
  y[1].x = a0.x - 0.5f*tx - s3*uy; y[1].y = a0.y - 0.5f*ty_ + s3*ux;
  y[2].x = a0.x - 0.5f*tx + s3*uy; y[2].y = a0.y - 0.5f*ty_ - s3*ux;
}

// 384-point DFT across one 64-lane wave. SIGN=-1 fwd, +1 inverse (no 1/N scale).
template<int SIGN>
__device__ __forceinline__ void fft384_wave(int l, const cf v[6], cf uA[3], cf uB[3]) {
  const float s3 = SIGN * 0.8660254037844386f;
  radix3(v[0], v[2], v[4], s3, uA);
  radix3(v[1], v[3], v[5], s3, uB);
  float sA, cA;
  __sincosf(SIGN * (2.0f * PI_F / 384.0f) * (float)l, &sA, &cA);
  cf wA1; wA1.x = cA; wA1.y = sA;
  cf wA2 = csqr(wA1);
  cf w6; w6.x = 0.5f; w6.y = s3;            // exp(SIGN*i*pi/3)
  cf wB1 = cmul(wA1, w6);
  cf wB2 = csqr(wB1);
  uA[1] = cmul(uA[1], wA1); uA[2] = cmul(uA[2], wA2);
  uB[1] = cmul(uB[1], wB1); uB[2] = cmul(uB[2], wB2);
  cf u = cmul(wA2, wA1);                    // exp(SIGN*i*pi*l/64): stage h=64 twiddle
  #pragma unroll
  for (int k1 = 0; k1 < 3; ++k1) {
    cf a = uA[k1], b = uB[k1];
    uA[k1] = cadd(a, b);
    uB[k1] = cmul(csub(a, b), u);
  }
  #pragma unroll
  for (int h = 32; h >= 1; h >>= 1) {
    u = csqr(u);                             // exp(SIGN*i*pi*l/h)
    const bool up = (l & h) != 0;
    #pragma unroll
    for (int k1 = 0; k1 < 3; ++k1) {
      cf pa = shflxor(uA[k1], h);
      cf pb = shflxor(uB[k1], h);
      cf na = up ? cmul(csub(uA[k1], pa), u) : cadd(uA[k1], pa);
      cf nb = up ? cmul(csub(uB[k1], pb), u) : cadd(uB[k1], pb);
      uA[k1] = na; uB[k1] = nb;
    }
  }
}

// ---------------- conv kernels ----------------
// Activations in PADDED NHWC bf16: act[b][y+1][x+1][c], row stride WP=386,
// c=64 contiguous. 1-px guard ring zeroed once per launch; conv stores only
// write interior -> guards stay zero -> halo reads need NO bounds checks and
// every conv_mid block takes the branch-free global_load_lds DMA path.

__global__ void repack_mid_k(const float* __restrict__ ws_mid, __hip_bfloat16* __restrict__ wrep) {
  const int idx = blockIdx.x * 256 + threadIdx.x;
  if (idx >= 7*9*64*64) return;
  const int ci = idx & 63, co = (idx >> 6) & 63, tap = (idx >> 12) % 9, i = idx / (9*4096);
  wrep[idx] = __float2bfloat16(ws_mid[(((size_t)i*64 + co)*64 + ci)*9 + tap]);
}

// zero the guard ring of both activation buffers (1540 px per image per buf)
__global__ void zero_guard_k(__hip_bfloat16* __restrict__ a, __hip_bfloat16* __restrict__ b2) {
  const int idx = blockIdx.x * 256 + threadIdx.x;
  if (idx >= 2*BB*1540*8) return;
  const int s = idx & 7; int rest = idx >> 3;
  const int px = rest % 1540; rest /= 1540;
  const int bb = rest & 3; const int buf = rest >> 2;
  int row, col;
  if (px < WP)        { row = 0;    col = px; }
  else if (px < 2*WP) { row = HH+1; col = px - WP; }
  else { const int k = px - 2*WP; row = 1 + (k >> 1); col = (k & 1) ? (WW+1) : 0; }
  __hip_bfloat16* base = buf ? b2 : a;
  *(uint4*)(base + ((size_t)bb*PP + (size_t)row*WP + col)*64 + s*8) = make_uint4(0u,0u,0u,0u);
}

__global__ void __launch_bounds__(256) conv_in_k(const float* __restrict__ xin,
                                                 const float* __restrict__ w,
                                                 const float* __restrict__ bias,
                                                 __hip_bfloat16* __restrict__ out) {
  __shared__ float tile[2][340];
  const int tx = threadIdx.x & 31, ty = threadIdx.x >> 5;
  const int x0 = blockIdx.x * 32, y0 = blockIdx.y * 8, b = blockIdx.z;
  for (int e = threadIdx.x; e < 680; e += 256) {
    int ci = e / 340, rr = e % 340;
    int iy = y0 - 1 + rr / 34, ix = x0 - 1 + rr % 34;
    float v = 0.f;
    if (iy >= 0 && iy < HH && ix >= 0 && ix < WW)
      v = xin[(b*2 + ci)*HW + iy*WW + ix];
    tile[ci][rr] = v;
  }
  __syncthreads();
  float acc[64];
  #pragma unroll
  for (int co = 0; co < 64; ++co) acc[co] = bias[co];
  #pragma unroll
  for (int ci = 0; ci < 2; ++ci) {
    float v0 = tile[ci][ty*34+tx],     v1 = tile[ci][ty*34+tx+1],     v2 = tile[ci][ty*34+tx+2];
    float v3 = tile[ci][(ty+1)*34+tx], v4 = tile[ci][(ty+1)*34+tx+1], v5 = tile[ci][(ty+1)*34+tx+2];
    float v6 = tile[ci][(ty+2)*34+tx], v7 = tile[ci][(ty+2)*34+tx+1], v8 = tile[ci][(ty+2)*34+tx+2];
    #pragma unroll
    for (int co = 0; co < 64; ++co) {
      const float* wp = w + co*18 + ci*9;
      float a = acc[co];
      a = fmaf(v0, wp[0], a); a = fmaf(v1, wp[1], a); a = fmaf(v2, wp[2], a);
      a = fmaf(v3, wp[3], a); a = fmaf(v4, wp[4], a); a = fmaf(v5, wp[5], a);
      a = fmaf(v6, wp[6], a); a = fmaf(v7, wp[7], a); a = fmaf(v8, wp[8], a);
      acc[co] = a;
    }
  }
  const size_t obase = ((size_t)b*PP + (size_t)(y0 + ty + 1)*WP + (x0 + tx + 1))*64;
  #pragma unroll
  for (int s = 0; s < 8; ++s) {
    uint4 u;
    __hip_bfloat16* hp = (__hip_bfloat16*)&u;
    #pragma unroll
    for (int j = 0; j < 8; ++j) hp[j] = __float2bfloat16(acc[s*8 + j]);
    *(uint4*)(out + obase + s*8) = u;
  }
}

// MFMA implicit-GEMM mid conv, v4:
// - 512 threads / 8 waves, 32x16 output tile, halo 34x18 = 78336 B LDS ->
//   2 blocks/CU = 16 waves/CU (was 12 theoretical / ~6 measured at 32x8).
// - padded layout: no bounds checks, ALL blocks use global_load_lds DMA.
// - keeps: rolled tap loop + one-tap-ahead weight dbuf (full unroll spills),
//   both-sides XOR channel-group swizzle (bank conflicts 2.95M -> 0.3M).
__global__ void __launch_bounds__(512, 4) conv_mid_mfma_k(
    const __hip_bfloat16* __restrict__ in,    // padded NHWC
    const __hip_bfloat16* __restrict__ wrep,  // [9][64][64] bf16
    const float* __restrict__ bias,
    __hip_bfloat16* __restrict__ out, int relu) {
  __shared__ __align__(16) __hip_bfloat16 atile[612*64];  // 78336 B
  const int tid = threadIdx.x;
  const int l = tid & 63, wv = tid >> 6;
  const int x0 = blockIdx.x * 32, y0 = blockIdx.y * 16, b = blockIdx.z;

  const int kseg = l >> 4;
  const int lr = l & 15;

  // weight prefetch for tap 0 (L2-resident, issued before staging drain)
  const __hip_bfloat16* wlane = wrep + lr*64 + kseg*8;
  short8 bf[4][2];
  #pragma unroll
  for (int nt = 0; nt < 4; ++nt) {
    bf[nt][0] = *(const short8*)(wlane + nt*1024);
    bf[nt][1] = *(const short8*)(wlane + nt*1024 + 32);
  }

  // ---- stage A-tile: 612 px * 8 slots = 4896 16B slots.
  // slot (p, s) <- channel-group s^(p&7) of halo pixel p (XOR swizzle).
  const __hip_bfloat16* inb = in + (size_t)b*PP*64;
  #pragma unroll
  for (int i = 0; i < 9; ++i) {
    const int j = i*512 + tid;
    const int p = j >> 3, s = j & 7;
    const int g = s ^ (p & 7);
    const __hip_bfloat16* src = inb + ((size_t)(y0 + p/34)*WP + (x0 + p%34))*64 + g*8;
    __builtin_amdgcn_global_load_lds(
        (const __attribute__((address_space(1))) void*)src,
        (__attribute__((address_space(3))) void*)(atile + (i*512 + wv*64)*8),
        16, 0, 0);
  }
  if (tid < 288) {                             // tail slots 4608..4895
    const int j = 4608 + tid;
    const int p = j >> 3, s = j & 7;
    const int g = s ^ (p & 7);
    uint4 v = *(const uint4*)(inb + ((size_t)(y0 + p/34)*WP + (x0 + p%34))*64 + g*8);
    *(uint4*)(atile + (size_t)j*8) = v;
  }

  floatx4 acc[4][4];
  #pragma unroll
  for (int mt = 0; mt < 4; ++mt)
    #pragma unroll
    for (int nt = 0; nt < 4; ++nt)
      acc[mt][nt] = (floatx4){0.f, 0.f, 0.f, 0.f};

  __syncthreads();

  #pragma unroll 1
  for (int tap = 0; tap < 9; ++tap) {
    short8 bfn[4][2];
    if (tap < 8) {
      const __hip_bfloat16* wn = wlane + (tap + 1)*4096;
      #pragma unroll
      for (int nt = 0; nt < 4; ++nt) {
        bfn[nt][0] = *(const short8*)(wn + nt*1024);
        bfn[nt][1] = *(const short8*)(wn + nt*1024 + 32);
      }
    }
    const int dy = tap / 3, dx = tap - dy*3;
    short8 af[4][2];
    #pragma unroll
    for (int mt = 0; mt < 4; ++mt) {
      const int ry = 2*wv + (mt >> 1) + dy;
      const int px = (mt & 1)*16 + lr + dx;
      const int p  = ry*34 + px;
      const int eo = p*64 + ((kseg ^ (p & 7)) << 3);   // swizzled elem offset
      af[mt][0] = *(const short8*)(atile + eo);
      af[mt][1] = *(const short8*)(atile + (eo ^ 32)); // (kseg+4)^(p&7) slot
    }
    #pragma unroll
    for (int mt = 0; mt < 4; ++mt)
      #pragma unroll
      for (int nt = 0; nt < 4; ++nt) {
        acc[mt][nt] = __builtin_amdgcn_mfma_f32_16x16x32_bf16(af[mt][0], bf[nt][0], acc[mt][nt], 0, 0, 0);
        acc[mt][nt] = __builtin_amdgcn_mfma_f32_16x16x32_bf16(af[mt][1], bf[nt][1], acc[mt][nt], 0, 0, 0);
      }
    if (tap < 8) {
      #pragma unroll
      for (int nt = 0; nt < 4; ++nt) { bf[nt][0] = bfn[nt][0]; bf[nt][1] = bfn[nt][1]; }
    }
  }

  // LDS-transpose epilogue -> coalesced 16B stores (reuses atile as [512][72])
  __syncthreads();
  __hip_bfloat16* otile = atile;
  #pragma unroll
  for (int mt = 0; mt < 4; ++mt) {
    const int row = 2*wv + (mt >> 1);
    #pragma unroll
    for (int nt = 0; nt < 4; ++nt) {
      const int ch = nt*16 + lr;
      const float bv = bias[ch];
      #pragma unroll
      for (int rr = 0; rr < 4; ++rr) {
        const int px = (mt & 1)*16 + kseg*4 + rr;
        float v = acc[mt][nt][rr] + bv;
        if (relu) v = fmaxf(v, 0.f);
        otile[(row*32 + px)*72 + ch] = __float2bfloat16(v);
      }
    }
  }
  __syncthreads();
  #pragma unroll
  for (int iter = 0; iter < 8; ++iter) {
    const int p = iter*64 + (tid >> 3), s = tid & 7;
    const int row = p >> 5, px = p & 31;
    uint4 v = *(const uint4*)(&otile[p*72 + s*8]);
    *(uint4*)(out + ((size_t)b*PP + (size_t)(y0 + row + 1)*WP + (x0 + px + 1))*64 + s*8) = v;
  }
}

// conv_out (co=2) + CG init, LDS-staged (padded input -> no bounds checks)
__global__ void __launch_bounds__(256) conv_out_k(const __hip_bfloat16* __restrict__ in,
                                                  const float* __restrict__ w,
                                                  const float* __restrict__ bias,
                                                  const float* __restrict__ xcur,
                                                  const float* __restrict__ under,
                                                  const float* __restrict__ lam,
                                                  cf* __restrict__ r, cf* __restrict__ p,
                                                  cf* __restrict__ xc, float* __restrict__ scL) {
  __shared__ __hip_bfloat16 atile[340*72];
  __shared__ float wl[2*64*9];
  __shared__ float wsum[4];
  const int tid = threadIdx.x;
  const int tx = tid & 31, ty = tid >> 5;
  const int x0 = blockIdx.x * 32, y0 = blockIdx.y * 8, b = blockIdx.z;

  for (int e = tid; e < 340*8; e += 256) {
    int pp = e >> 3, s = e & 7;
    uint4 v = *(const uint4*)(in + ((size_t)b*PP + (size_t)(y0 + pp/34)*WP + (x0 + pp%34))*64 + s*8);
    *(uint4*)(&atile[pp*72 + s*8]) = v;
  }
  for (int e = tid; e < 2*64*9; e += 256) wl[e] = w[e];
  __syncthreads();

  float a0 = bias[0], a1 = bias[1];
  #pragma unroll 1
  for (int tap = 0; tap < 9; ++tap) {
    const int dy = tap / 3, dx = tap - dy*3;
    const __hip_bfloat16* ap = &atile[((ty + dy)*34 + tx + dx)*72];
    #pragma unroll
    for (int s = 0; s < 8; ++s) {
      short8 v8 = *(const short8*)(ap + s*8);
      const __hip_bfloat16* hv = (const __hip_bfloat16*)&v8;
      #pragma unroll
      for (int j = 0; j < 8; ++j) {
        const float f = __bfloat162float(hv[j]);
        a0 = fmaf(f, wl[(s*8 + j)*9 + tap], a0);
        a1 = fmaf(f, wl[(64 + s*8 + j)*9 + tap], a1);
      }
    }
  }
  const float lamv = lam[0];
  const int y = y0 + ty, x = x0 + tx;
  const int idx2 = y*WW + x;
  float xv0 = xcur[b*2*HW + idx2],  xv1 = xcur[b*2*HW + HW + idx2];
  float u0  = under[b*2*HW + idx2], u1  = under[b*2*HW + HW + idx2];
  float r0 = u0 + lamv * (xv0 + a0);
  float r1 = u1 + lamv * (xv1 + a1);
  const int cidx = b*HW + idx2;
  cf vv; vv.x = r0; vv.y = r1;
  r[cidx] = vv; p[cidx] = vv;
  cf zz; zz.x = 0.f; zz.y = 0.f; xc[cidx] = zz;
  float partial = r0*r0 + r1*r1;
  for (int off = 32; off; off >>= 1) partial += __shfl_down(partial, off);
  const int l = tid & 63, wvid = tid >> 6;
  if (l == 0) wsum[wvid] = partial;
  __syncthreads();
  if (tid == 0) atomicAdd(&scL[b], wsum[0]+wsum[1]+wsum[2]+wsum[3]);
}

// ---------------- CG / FFT kernels ----------------
// scL (128 floats/layer): rtr[it*4+b] (it 0..9), pAp[40+it*4+b], ApAp[80+it*4+b].
// 3 dispatches/iter. rtr recurrence: rtr_new = a^2*ApAp - rtr (Hermitian A).

__global__ void __launch_bounds__(256) pass_a_k(const cf* __restrict__ rold, cf* __restrict__ rnew,
                                                const cf* __restrict__ pold, cf* __restrict__ pnew,
                                                cf* __restrict__ xc, const cf* __restrict__ Ap,
                                                const cf* __restrict__ csm, cf* __restrict__ t,
                                                float* __restrict__ scL, int it) {
  __shared__ cf rowbuf[4][434];
  const int l = threadIdx.x & 63, wv = threadIdx.x >> 6;
  const int y = blockIdx.x * 4 + wv;
  const int c = blockIdx.y, b = blockIdx.z;
  const int rowoff = b*HW + y*WW;
  cf pv[6];
  if (it == 0) {
    #pragma unroll
    for (int m = 0; m < 6; ++m) pv[m] = pold[rowoff + l + 64*m];
  } else {
    const float rtrp  = scL[(it-1)*4 + b];
    const float pApp  = scL[40 + (it-1)*4 + b];
    const float ApApp = scL[80 + (it-1)*4 + b];
    const float alpha = rtrp / pApp;
    const float rtrn  = alpha*alpha*ApApp - rtrp;
    const float beta  = rtrn / rtrp;
    if (blockIdx.x == 0 && c == 0 && threadIdx.x == 0) scL[it*4 + b] = rtrn;
    #pragma unroll
    for (int m = 0; m < 6; ++m) {
      const int idx = rowoff + l + 64*m;
      cf rv = rold[idx];
      cf av = Ap[idx];
      rv.x -= alpha*av.x; rv.y -= alpha*av.y;
      cf po = pold[idx];
      pv[m].x = rv.x + beta*po.x; pv[m].y = rv.y + beta*po.y;
      if (c == 0) {
        rnew[idx] = rv;
        pnew[idx] = pv[m];
        cf xv = xc[idx]; xv.x += alpha*po.x; xv.y += alpha*po.y; xc[idx] = xv;
      }
    }
  }
  const cf* crow = csm + (b*CC + c)*HW + y*WW;
  cf v[6];
  #pragma unroll
  for (int m = 0; m < 6; ++m) v[m] = cmul(crow[l + 64*m], pv[m]);
  cf uA[3], uB[3];
  fft384_wave<-1>(l, v, uA, uB);
  const int R3 = 3 * brev7(l);
  cf* rb = rowbuf[wv];                  // wave-private
  #pragma unroll
  for (int k1 = 0; k1 < 3; ++k1) { rb[padi(k1 + R3)] = uA[k1]; rb[padi(k1 + R3 + 3)] = uB[k1]; }
  cf* trow = t + (b*CC + c)*HW + y*WW;
  #pragma unroll
  for (int m = 0; m < 6; ++m) trow[l + 64*m] = rb[padi(l + 64*m)];
}

__global__ void __launch_bounds__(256) pass_b_k(cf* __restrict__ t, const float* __restrict__ mask) {
  __shared__ cf tile[431*9];
  const int b = blockIdx.z, c = blockIdx.y, x0 = blockIdx.x * 8;
  cf* base = t + (b*CC + c)*HW;
  for (int e = threadIdx.x; e < 3072; e += 256) {
    int y = e >> 3, xx = e & 7;
    tile[padi(y)*9 + xx] = base[y*WW + x0 + xx];
  }
  __syncthreads();
  const int l = threadIdx.x & 63, wv = threadIdx.x >> 6;
  const int R3 = 3 * brev7(l);
  for (int rep = 0; rep < 2; ++rep) {
    const int xx = wv*2 + rep, x = x0 + xx;
    cf v[6];
    #pragma unroll
    for (int m = 0; m < 6; ++m) v[m] = tile[padi(l + 64*m)*9 + xx];
    cf uA[3], uB[3];
    fft384_wave<-1>(l, v, uA, uB);
    const float* mrow = mask + b*HW + x;
    #pragma unroll
    for (int k1 = 0; k1 < 3; ++k1) {
      float mA = mrow[(k1 + R3)*WW], mB = mrow[(k1 + R3 + 3)*WW];
      uA[k1].x *= mA; uA[k1].y *= mA; uB[k1].x *= mB; uB[k1].y *= mB;
    }
    __syncthreads();
    #pragma unroll
    for (int k1 = 0; k1 < 3; ++k1) { tile[padi(k1 + R3)*9 + xx] = uA[k1]; tile[padi(k1 + R3 + 3)*9 + xx] = uB[k1]; }
    __syncthreads();
    #pragma unroll
    for (int m = 0; m < 6; ++m) v[m] = tile[padi(l + 64*m)*9 + xx];
    fft384_wave<1>(l, v, uA, uB);
    const float s = 1.0f / 384.0f;
    #pragma unroll
    for (int k1 = 0; k1 < 3; ++k1) {
      uA[k1].x *= s; uA[k1].y *= s; uB[k1].x *= s; uB[k1].y *= s;
      tile[padi(k1 + R3)*9 + xx] = uA[k1]; tile[padi(k1 + R3 + 3)*9 + xx] = uB[k1];
    }
    __syncthreads();
  }
  for (int e = threadIdx.x; e < 3072; e += 256) {
    int y = e >> 3, xx = e & 7;
    base[y*WW + x0 + xx] = tile[padi(y)*9 + xx];
  }
}

// pass_c: one y-row per block (HH x BB grid), 8 coils split 2/wave, LDS reduce.
__global__ void __launch_bounds__(256) pass_c_k(const cf* __restrict__ t, const cf* __restrict__ csm,
                                                const cf* __restrict__ p, cf* __restrict__ Ap,
                                                const float* __restrict__ lam,
                                                float* __restrict__ scL, int it) {
  __shared__ cf rowbuf[4][434];
  __shared__ cf redbuf[3][384];
  const int l = threadIdx.x & 63, wv = threadIdx.x >> 6;
  const int y = blockIdx.x, b = blockIdx.y;
  const int R3 = 3 * brev7(l);
  cf* rb = rowbuf[wv];                  // wave-private
  cf acc[6] = {};
  #pragma unroll 1
  for (int ci = 0; ci < 2; ++ci) {
    const int c = wv*2 + ci;
    const cf* trow = t + (b*CC + c)*HW + y*WW;
    cf v[6];
    #pragma unroll
    for (int m = 0; m < 6; ++m) v[m] = trow[l + 64*m];
    cf uA[3], uB[3];
    fft384_wave<1>(l, v, uA, uB);
    #pragma unroll
    for (int k1 = 0; k1 < 3; ++k1) { rb[padi(k1 + R3)] = uA[k1]; rb[padi(k1 + R3 + 3)] = uB[k1]; }
    const cf* crow = csm + (b*CC + c)*HW + y*WW;
    #pragma unroll
    for (int m = 0; m < 6; ++m) {
      cf cs = crow[l + 64*m];
      cf wz = rb[padi(l + 64*m)];
      acc[m].x += cs.x*wz.x + cs.y*wz.y;
      acc[m].y += cs.x*wz.y - cs.y*wz.x;
    }
  }
  if (wv > 0) {
    #pragma unroll
    for (int m = 0; m < 6; ++m) redbuf[wv - 1][l + 64*m] = acc[m];
  }
  __syncthreads();
  if (wv == 0) {
    #pragma unroll
    for (int m = 0; m < 6; ++m) {
      #pragma unroll
      for (int j = 0; j < 3; ++j) {
        cf o = redbuf[j][l + 64*m];
        acc[m].x += o.x; acc[m].y += o.y;
      }
    }
    const float lamv = lam[0];
    const float sc384 = 1.0f / 384.0f;
    const cf* prow = p + b*HW + y*WW;
    cf* aprow = Ap + b*HW + y*WW;
    float partial = 0.f, partial2 = 0.f;
    #pragma unroll
    for (int m = 0; m < 6; ++m) {
      cf pv = prow[l + 64*m];
      cf ap; ap.x = acc[m].x*sc384 + lamv*pv.x; ap.y = acc[m].y*sc384 + lamv*pv.y;
      aprow[l + 64*m] = ap;
      partial  += pv.x*ap.x + pv.y*ap.y;
      partial2 += ap.x*ap.x + ap.y*ap.y;
    }
    #pragma unroll
    for (int off = 32; off; off >>= 1) {
      partial  += __shfl_down(partial, off);
      partial2 += __shfl_down(partial2, off);
    }
    if (l == 0) {
      atomicAdd(&scL[40 + it*4 + b], partial);
      atomicAdd(&scL[80 + it*4 + b], partial2);
    }
  }
}

// final x = xc + alpha9 * p9, planar output
__global__ void __launch_bounds__(256) final_x_k(const cf* __restrict__ xc, const cf* __restrict__ p9,
                                                 const float* __restrict__ scL, float* __restrict__ out) {
  const int idx = blockIdx.x * 256 + threadIdx.x;
  const int b = idx / HW;
  const int rem = idx - b*HW;
  const float alpha = scL[(CGITERS-1)*4 + b] / scL[40 + (CGITERS-1)*4 + b];
  cf xv = xc[idx], pv = p9[idx];
  xv.x += alpha*pv.x; xv.y += alpha*pv.y;
  out[b*2*HW + rem] = xv.x;
  out[b*2*HW + HW + rem] = xv.y;
}

__global__ void zero_sc_k(float* sc) {
  for (int i = threadIdx.x; i < NLAYERS*128; i += 256) sc[i] = 0.f;
}

extern "C" void kernel_launch(void* const* d_in, const int* in_sizes, int n_in,
                              void* d_out, int out_size, void* d_ws, size_t ws_size,
                              hipStream_t stream) {
  (void)in_sizes; (void)n_in; (void)out_size; (void)ws_size;
  const float* under  = (const float*)d_in[0];
  const cf*    csm    = (const cf*)d_in[1];
  const float* mask   = (const float*)d_in[2];
  const float* lam    = (const float*)d_in[3];
  const float* w_in   = (const float*)d_in[4];
  const float* b_in   = (const float*)d_in[5];
  const float* ws_mid = (const float*)d_in[6];
  const float* bs_mid = (const float*)d_in[7];
  const float* w_out  = (const float*)d_in[8];
  const float* b_out  = (const float*)d_in[9];
  float* xcur = (float*)d_out;

  char* bws = (char*)d_ws;
  size_t off = 0;
  auto carve = [&](size_t bytes) { char* pp = bws + off; off += (bytes + 255) & ~(size_t)255; return (void*)pp; };
  __hip_bfloat16* actA = (__hip_bfloat16*)carve((size_t)BB*PP*64*2);
  __hip_bfloat16* actB = (__hip_bfloat16*)carve((size_t)BB*PP*64*2);
  cf* t     = (cf*)carve((size_t)BB*CC*HW*8);
  cf* rbuf0 = (cf*)carve((size_t)BB*HW*8);
  cf* rbuf1 = (cf*)carve((size_t)BB*HW*8);
  cf* pbuf0 = (cf*)carve((size_t)BB*HW*8);
  cf* pbuf1 = (cf*)carve((size_t)BB*HW*8);
  cf* xc    = (cf*)carve((size_t)BB*HW*8);
  cf* Ap    = (cf*)carve((size_t)BB*HW*8);
  float* sc = (float*)carve(4096);
  __hip_bfloat16* wrep = (__hip_bfloat16*)carve((size_t)7*9*64*64*2);

  hipMemcpyAsync(xcur, under, (size_t)BB*2*HW*sizeof(float), hipMemcpyDeviceToDevice, stream);

  zero_sc_k<<<1, 256, 0, stream>>>(sc);
  repack_mid_k<<<(7*9*64*64 + 255)/256, 256, 0, stream>>>(ws_mid, wrep);
  zero_guard_k<<<(2*BB*1540*8 + 255)/256, 256, 0, stream>>>(actA, actB);

  dim3 cgrid(WW/32, HH/8, BB);       // conv_in / conv_out (32x8 tiles)
  dim3 cmgrid(WW/32, HH/16, BB);     // conv_mid (32x16 tiles, 512 thr)
  dim3 agrid(HH/4, CC, BB);
  dim3 bgrid(WW/8, CC, BB);
  dim3 c2grid(HH, BB);               // pass_c: one row per block
  const int egrid = BB*HW/256;

  __hip_bfloat16* bufs[2] = { actA, actB };
  cf* rb[2] = { rbuf0, rbuf1 };
  cf* pb[2] = { pbuf0, pbuf1 };

  for (int layer = 0; layer < NLAYERS; ++layer) {
    float* scL = sc + layer*128;
    conv_in_k<<<cgrid, 256, 0, stream>>>(xcur, w_in, b_in, bufs[0]);
    for (int i = 0; i < 7; ++i) {
      conv_mid_mfma_k<<<cmgrid, 512, 0, stream>>>(bufs[i & 1], wrep + (size_t)i*9*4096,
                                                  bs_mid + i*64, bufs[(i + 1) & 1], (i % 2 == 0) ? 1 : 0);
    }
    conv_out_k<<<cgrid, 256, 0, stream>>>(bufs[1], w_out, b_out, xcur, under, lam,
                                          rbuf0, pbuf0, xc, scL);
    for (int it = 0; it < CGITERS; ++it) {
      cf* rold = rb[(it + 1) & 1];
      cf* rnew = rb[it & 1];
      cf* pold = pb[(it + 1) & 1];
      cf* pnew = pb[it & 1];
      if (it == 0) { rold = rbuf0; pold = pbuf0; rnew = rbuf0; pnew = pbuf0; }
      pass_a_k<<<agrid, 256, 0, stream>>>(rold, rnew, pold, pnew, xc, Ap, csm, t, scL, it);
      pass_b_k<<<bgrid, 256, 0, stream>>>(t, mask);
      pass_c_k<<<c2grid, 256, 0, stream>>>(t, csm, pnew, Ap, lam, scL, it);
    }
    final_x_k<<<egrid, 256, 0, stream>>>(xc, pb[(CGITERS - 1) & 1], scL, xcur);
  }
}

// Round 4
// 10053.708 us; speedup vs baseline: 1.0801x; 1.0801x over previous
//
#include <hip/hip_runtime.h>
#include <hip/hip_bf16.h>
#include <math.h>

#define HH 384
#define WW 384
#define HW (HH*WW)
#define WP 386              // padded row stride (1-px guard ring)
#define PP (386*386)        // padded image pixels
#define BB 4
#define CC 8
#define NLAYERS 5
#define CGITERS 10
#define PI_F 3.14159265358979323846f

typedef __attribute__((ext_vector_type(8))) short short8;
typedef __attribute__((ext_vector_type(4))) float floatx4;

struct cf { float x, y; };
__device__ __forceinline__ cf cadd(cf a, cf b){ cf r; r.x=a.x+b.x; r.y=a.y+b.y; return r; }
__device__ __forceinline__ cf csub(cf a, cf b){ cf r; r.x=a.x-b.x; r.y=a.y-b.y; return r; }
__device__ __forceinline__ cf cmul(cf a, cf b){ cf r; r.x=a.x*b.x - a.y*b.y; r.y=a.x*b.y + a.y*b.x; return r; }
__device__ __forceinline__ cf csqr(cf a){ cf r; r.x = a.x*a.x - a.y*a.y; r.y = 2.f*a.x*a.y; return r; }
__device__ __forceinline__ cf shflxor(cf v, int m){ cf r; r.x = __shfl_xor(v.x, m); r.y = __shfl_xor(v.y, m); return r; }
__device__ __forceinline__ int brev7(int l){ return (int)(__brev((unsigned)l) >> 25); }
__device__ __forceinline__ int padi(int i){ return i + (i >> 3); }

__device__ __forceinline__ void radix3(cf a0, cf a1, cf a2, float s3, cf y[3]) {
  float tx = a1.x + a2.x, ty_ = a1.y + a2.y;
  float ux = a1.x - a2.x, uy = a1.y - a2.y;
  y[0].x = a0.x + tx;              y[0].y = a0.y + ty_;
  y[1].x = a0.x - 0.5f*tx - s3*uy; y[1].y = a0.y - 0.5f*ty_ + s3*ux;
  y[2].x = a0.x - 0.5f*tx + s3*uy; y[2].y = a0.y - 0.5f*ty_ - s3*ux;
}

// 384-point DFT across one 64-lane wave. SIGN=-1 fwd, +1 inverse (no 1/N scale).
template<int SIGN>
__device__ __forceinline__ void fft384_wave(int l, const cf v[6], cf uA[3], cf uB[3]) {
  const float s3 = SIGN * 0.8660254037844386f;
  radix3(v[0], v[2], v[4], s3, uA);
  radix3(v[1], v[3], v[5], s3, uB);
  float sA, cA;
  __sincosf(SIGN * (2.0f * PI_F / 384.0f) * (float)l, &sA, &cA);
  cf wA1; wA1.x = cA; wA1.y = sA;
  cf wA2 = csqr(wA1);
  cf w6; w6.x = 0.5f; w6.y = s3;            // exp(SIGN*i*pi/3)
  cf wB1 = cmul(wA1, w6);
  cf wB2 = csqr(wB1);
  uA[1] = cmul(uA[1], wA1); uA[2] = cmul(uA[2], wA2);
  uB[1] = cmul(uB[1], wB1); uB[2] = cmul(uB[2], wB2);
  cf u = cmul(wA2, wA1);                    // exp(SIGN*i*pi*l/64): stage h=64 twiddle
  #pragma unroll
  for (int k1 = 0; k1 < 3; ++k1) {
    cf a = uA[k1], b = uB[k1];
    uA[k1] = cadd(a, b);
    uB[k1] = cmul(csub(a, b), u);
  }
  #pragma unroll
  for (int h = 32; h >= 1; h >>= 1) {
    u = csqr(u);                             // exp(SIGN*i*pi*l/h)
    const bool up = (l & h) != 0;
    #pragma unroll
    for (int k1 = 0; k1 < 3; ++k1) {
      cf pa = shflxor(uA[k1], h);
      cf pb = shflxor(uB[k1], h);
      cf na = up ? cmul(csub(uA[k1], pa), u) : cadd(uA[k1], pa);
      cf nb = up ? cmul(csub(uB[k1], pb), u) : cadd(uB[k1], pb);
      uA[k1] = na; uB[k1] = nb;
    }
  }
}

// ---------------- conv kernels ----------------
// Activations in PADDED NHWC bf16: act[b][y+1][x+1][c], row stride WP=386,
// c=64 contiguous. 1-px guard ring zeroed once per launch; conv stores only
// write interior -> guards stay zero -> halo reads need NO bounds checks.

__global__ void repack_mid_k(const float* __restrict__ ws_mid, __hip_bfloat16* __restrict__ wrep) {
  const int idx = blockIdx.x * 256 + threadIdx.x;
  if (idx >= 7*9*64*64) return;
  const int ci = idx & 63, co = (idx >> 6) & 63, tap = (idx >> 12) % 9, i = idx / (9*4096);
  wrep[idx] = __float2bfloat16(ws_mid[(((size_t)i*64 + co)*64 + ci)*9 + tap]);
}

// zero the guard ring of both activation buffers (1540 px per image per buf)
__global__ void zero_guard_k(__hip_bfloat16* __restrict__ a, __hip_bfloat16* __restrict__ b2) {
  const int idx = blockIdx.x * 256 + threadIdx.x;
  if (idx >= 2*BB*1540*8) return;
  const int s = idx & 7; int rest = idx >> 3;
  const int px = rest % 1540; rest /= 1540;
  const int bb = rest & 3; const int buf = rest >> 2;
  int row, col;
  if (px < WP)        { row = 0;    col = px; }
  else if (px < 2*WP) { row = HH+1; col = px - WP; }
  else { const int k = px - 2*WP; row = 1 + (k >> 1); col = (k & 1) ? (WW+1) : 0; }
  __hip_bfloat16* base = buf ? b2 : a;
  *(uint4*)(base + ((size_t)bb*PP + (size_t)row*WP + col)*64 + s*8) = make_uint4(0u,0u,0u,0u);
}

__global__ void __launch_bounds__(256) conv_in_k(const float* __restrict__ xin,
                                                 const float* __restrict__ w,
                                                 const float* __restrict__ bias,
                                                 __hip_bfloat16* __restrict__ out) {
  __shared__ float tile[2][340];
  const int tx = threadIdx.x & 31, ty = threadIdx.x >> 5;
  const int x0 = blockIdx.x * 32, y0 = blockIdx.y * 8, b = blockIdx.z;
  for (int e = threadIdx.x; e < 680; e += 256) {
    int ci = e / 340, rr = e % 340;
    int iy = y0 - 1 + rr / 34, ix = x0 - 1 + rr % 34;
    float v = 0.f;
    if (iy >= 0 && iy < HH && ix >= 0 && ix < WW)
      v = xin[(b*2 + ci)*HW + iy*WW + ix];
    tile[ci][rr] = v;
  }
  __syncthreads();
  float acc[64];
  #pragma unroll
  for (int co = 0; co < 64; ++co) acc[co] = bias[co];
  #pragma unroll
  for (int ci = 0; ci < 2; ++ci) {
    float v0 = tile[ci][ty*34+tx],     v1 = tile[ci][ty*34+tx+1],     v2 = tile[ci][ty*34+tx+2];
    float v3 = tile[ci][(ty+1)*34+tx], v4 = tile[ci][(ty+1)*34+tx+1], v5 = tile[ci][(ty+1)*34+tx+2];
    float v6 = tile[ci][(ty+2)*34+tx], v7 = tile[ci][(ty+2)*34+tx+1], v8 = tile[ci][(ty+2)*34+tx+2];
    #pragma unroll
    for (int co = 0; co < 64; ++co) {
      const float* wp = w + co*18 + ci*9;
      float a = acc[co];
      a = fmaf(v0, wp[0], a); a = fmaf(v1, wp[1], a); a = fmaf(v2, wp[2], a);
      a = fmaf(v3, wp[3], a); a = fmaf(v4, wp[4], a); a = fmaf(v5, wp[5], a);
      a = fmaf(v6, wp[6], a); a = fmaf(v7, wp[7], a); a = fmaf(v8, wp[8], a);
      acc[co] = a;
    }
  }
  const size_t obase = ((size_t)b*PP + (size_t)(y0 + ty + 1)*WP + (x0 + tx + 1))*64;
  #pragma unroll
  for (int s = 0; s < 8; ++s) {
    uint4 u;
    __hip_bfloat16* hp = (__hip_bfloat16*)&u;
    #pragma unroll
    for (int j = 0; j < 8; ++j) hp[j] = __float2bfloat16(acc[s*8 + j]);
    *(uint4*)(out + obase + s*8) = u;
  }
}

// MFMA implicit-GEMM mid conv, v5: PERSISTENT + DOUBLE-BUFFERED.
// Lesson r1/r3: working set is ~64 acc (unified AGPR) + ~105 VGPR -> any
// config demanding >2 waves/SIMD spills (r3: WRITE 217MB, VGPR capped 64).
// So TLP is capped at 8 waves/CU; hide staging latency with ILP instead:
// - 256 blocks x 512 thr, 1 block/CU; each block grid-strides ~4.5 tiles.
// - two 78.8KB LDS tile buffers; issue next tile's global_load_lds DMAs
//   (10/thread) BEFORE computing current tile; counted s_waitcnt vmcnt(10)
//   (never 0 in steady state) so ~78KB streams under the 9-tap MFMA loop.
// - raw s_barrier + manual waitcnt (a __syncthreads would drain the
//   prefetch queue — the m97 stall).
// - compute/epilogue bodies identical to the r3-verified 512-thread code.
__global__ void __launch_bounds__(512, 2) conv_mid_mfma_k(
    const __hip_bfloat16* __restrict__ in,    // padded NHWC
    const __hip_bfloat16* __restrict__ wrep,  // [9][64][64] bf16
    const float* __restrict__ bias,
    __hip_bfloat16* __restrict__ out, int relu) {
  // 4928 slots/buffer: 4896 real (612 px * 8) + 32 pad for the partial-exec
  // tail DMA of wave 4. 2 * 4928 * 16B = 157696 B LDS.
  __shared__ __align__(16) __hip_bfloat16 atile[2][4928*8];
  const int tid = threadIdx.x;
  const int l = tid & 63, wv = tid >> 6;
  const int kseg = l >> 4;
  const int lr = l & 15;
  const __hip_bfloat16* wlane = wrep + lr*64 + kseg*8;

  const int NT = 12*24*4;   // tiles: x(12) fastest, then y(24), then b(4)

  // stage tile tt into buffer bi: slot (p,s) <- channel-group s^(p&7) of
  // halo pixel p (both-sides XOR swizzle, r2-verified).
  auto stage = [&](int bi, int tt) {
    const int tx_ = tt % 12, ty_ = (tt / 12) % 24, b = tt / 288;
    const int x0 = tx_ * 32, y0 = ty_ * 16;
    const __hip_bfloat16* inb = in + (size_t)b*PP*64;
    __hip_bfloat16* A = &atile[bi][0];
    #pragma unroll
    for (int i = 0; i < 9; ++i) {
      const int j = i*512 + tid;                 // 16B slot index
      const int p = j >> 3, s = j & 7;
      const int g = s ^ (p & 7);
      const __hip_bfloat16* src = inb + ((size_t)(y0 + p/34)*WP + (x0 + p%34))*64 + g*8;
      __builtin_amdgcn_global_load_lds(
          (const __attribute__((address_space(1))) void*)src,
          (__attribute__((address_space(3))) void*)(A + (i*512 + wv*64)*8),
          16, 0, 0);
    }
    // tail slots 4608..4895 (wave 4 half-exec; pad slots 4896..4927 absorb)
    if (tid < 288) {
      const int j = 4608 + tid;
      const int jj = j < 4896 ? j : 4895;        // valid src for masked lanes
      const int p = jj >> 3, s = jj & 7;
      const int g = s ^ (p & 7);
      const __hip_bfloat16* src = inb + ((size_t)(y0 + p/34)*WP + (x0 + p%34))*64 + g*8;
      __builtin_amdgcn_global_load_lds(
          (const __attribute__((address_space(1))) void*)src,
          (__attribute__((address_space(3))) void*)(A + (4608 + wv*64)*8),
          16, 0, 0);
    }
  };
  // per-wave DMA count per stage: waves 0-4 -> 10, waves 5-7 -> 9

  int t = blockIdx.x;
  int cur = 0;
  stage(cur, t);

  #pragma unroll 1
  for (; t < NT; t += 256) {
    const int tx_ = t % 12, ty_ = (t / 12) % 24, b = t / 288;
    const int x0 = tx_ * 32, y0 = ty_ * 16;
    const bool more = (t + 256) < NT;
    if (more) stage(cur ^ 1, t + 256);

    // wait for CURRENT buffer's DMAs; allow NEXT buffer's to stay in flight.
    if (more) {
      if (wv < 5) asm volatile("s_waitcnt vmcnt(10)" ::: "memory");
      else        asm volatile("s_waitcnt vmcnt(9)"  ::: "memory");
    } else {
      asm volatile("s_waitcnt vmcnt(0)" ::: "memory");
    }
    __builtin_amdgcn_s_barrier();
    __builtin_amdgcn_sched_barrier(0);

    const __hip_bfloat16* A = &atile[cur][0];

    // weight prefetch for tap 0
    short8 bf[4][2];
    #pragma unroll
    for (int nt = 0; nt < 4; ++nt) {
      bf[nt][0] = *(const short8*)(wlane + nt*1024);
      bf[nt][1] = *(const short8*)(wlane + nt*1024 + 32);
    }

    floatx4 acc[4][4];
    #pragma unroll
    for (int mt = 0; mt < 4; ++mt)
      #pragma unroll
      for (int nt = 0; nt < 4; ++nt)
        acc[mt][nt] = (floatx4){0.f, 0.f, 0.f, 0.f};

    #pragma unroll 1
    for (int tap = 0; tap < 9; ++tap) {
      short8 bfn[4][2];
      if (tap < 8) {
        const __hip_bfloat16* wn = wlane + (tap + 1)*4096;
        #pragma unroll
        for (int nt = 0; nt < 4; ++nt) {
          bfn[nt][0] = *(const short8*)(wn + nt*1024);
          bfn[nt][1] = *(const short8*)(wn + nt*1024 + 32);
        }
      }
      const int dy = tap / 3, dx = tap - dy*3;
      short8 af[4][2];
      #pragma unroll
      for (int mt = 0; mt < 4; ++mt) {
        const int ry = 2*wv + (mt >> 1) + dy;
        const int px = (mt & 1)*16 + lr + dx;
        const int p  = ry*34 + px;
        const int eo = p*64 + ((kseg ^ (p & 7)) << 3);   // swizzled elem offset
        af[mt][0] = *(const short8*)(A + eo);
        af[mt][1] = *(const short8*)(A + (eo ^ 32));     // (kseg+4)^(p&7) slot
      }
      #pragma unroll
      for (int mt = 0; mt < 4; ++mt)
        #pragma unroll
        for (int nt = 0; nt < 4; ++nt) {
          acc[mt][nt] = __builtin_amdgcn_mfma_f32_16x16x32_bf16(af[mt][0], bf[nt][0], acc[mt][nt], 0, 0, 0);
          acc[mt][nt] = __builtin_amdgcn_mfma_f32_16x16x32_bf16(af[mt][1], bf[nt][1], acc[mt][nt], 0, 0, 0);
        }
      if (tap < 8) {
        #pragma unroll
        for (int nt = 0; nt < 4; ++nt) { bf[nt][0] = bfn[nt][0]; bf[nt][1] = bfn[nt][1]; }
      }
    }

    // all waves done reading A before overwriting it as otile
    asm volatile("s_waitcnt lgkmcnt(0)" ::: "memory");
    __builtin_amdgcn_s_barrier();

    // LDS-transpose epilogue -> coalesced 16B stores (A reused as [512][72])
    __hip_bfloat16* otile = &atile[cur][0];
    #pragma unroll
    for (int mt = 0; mt < 4; ++mt) {
      const int row = 2*wv + (mt >> 1);
      #pragma unroll
      for (int nt = 0; nt < 4; ++nt) {
        const int ch = nt*16 + lr;
        const float bv = bias[ch];
        #pragma unroll
        for (int rr = 0; rr < 4; ++rr) {
          const int px = (mt & 1)*16 + kseg*4 + rr;
          float v = acc[mt][nt][rr] + bv;
          if (relu) v = fmaxf(v, 0.f);
          otile[(row*32 + px)*72 + ch] = __float2bfloat16(v);
        }
      }
    }
    asm volatile("s_waitcnt lgkmcnt(0)" ::: "memory");
    __builtin_amdgcn_s_barrier();
    #pragma unroll
    for (int iter = 0; iter < 8; ++iter) {
      const int p = iter*64 + (tid >> 3), s = tid & 7;
      const int row = p >> 5, px = p & 31;
      uint4 v = *(const uint4*)(&otile[p*72 + s*8]);
      *(uint4*)(out + ((size_t)b*PP + (size_t)(y0 + row + 1)*WP + (x0 + px + 1))*64 + s*8) = v;
    }
    // epilogue reads of otile done before next iteration's DMA overwrites it
    asm volatile("s_waitcnt lgkmcnt(0)" ::: "memory");
    __builtin_amdgcn_s_barrier();

    cur ^= 1;
  }
}

// conv_out (co=2) + CG init, LDS-staged (padded input -> no bounds checks)
__global__ void __launch_bounds__(256) conv_out_k(const __hip_bfloat16* __restrict__ in,
                                                  const float* __restrict__ w,
                                                  const float* __restrict__ bias,
                                                  const float* __restrict__ xcur,
                                                  const float* __restrict__ under,
                                                  const float* __restrict__ lam,
                                                  cf* __restrict__ r, cf* __restrict__ p,
                                                  cf* __restrict__ xc, float* __restrict__ scL) {
  __shared__ __hip_bfloat16 atile[340*72];
  __shared__ float wl[2*64*9];
  __shared__ float wsum[4];
  const int tid = threadIdx.x;
  const int tx = tid & 31, ty = tid >> 5;
  const int x0 = blockIdx.x * 32, y0 = blockIdx.y * 8, b = blockIdx.z;

  for (int e = tid; e < 340*8; e += 256) {
    int pp = e >> 3, s = e & 7;
    uint4 v = *(const uint4*)(in + ((size_t)b*PP + (size_t)(y0 + pp/34)*WP + (x0 + pp%34))*64 + s*8);
    *(uint4*)(&atile[pp*72 + s*8]) = v;
  }
  for (int e = tid; e < 2*64*9; e += 256) wl[e] = w[e];
  __syncthreads();

  float a0 = bias[0], a1 = bias[1];
  #pragma unroll 1
  for (int tap = 0; tap < 9; ++tap) {
    const int dy = tap / 3, dx = tap - dy*3;
    const __hip_bfloat16* ap = &atile[((ty + dy)*34 + tx + dx)*72];
    #pragma unroll
    for (int s = 0; s < 8; ++s) {
      short8 v8 = *(const short8*)(ap + s*8);
      const __hip_bfloat16* hv = (const __hip_bfloat16*)&v8;
      #pragma unroll
      for (int j = 0; j < 8; ++j) {
        const float f = __bfloat162float(hv[j]);
        a0 = fmaf(f, wl[(s*8 + j)*9 + tap], a0);
        a1 = fmaf(f, wl[(64 + s*8 + j)*9 + tap], a1);
      }
    }
  }
  const float lamv = lam[0];
  const int y = y0 + ty, x = x0 + tx;
  const int idx2 = y*WW + x;
  float xv0 = xcur[b*2*HW + idx2],  xv1 = xcur[b*2*HW + HW + idx2];
  float u0  = under[b*2*HW + idx2], u1  = under[b*2*HW + HW + idx2];
  float r0 = u0 + lamv * (xv0 + a0);
  float r1 = u1 + lamv * (xv1 + a1);
  const int cidx = b*HW + idx2;
  cf vv; vv.x = r0; vv.y = r1;
  r[cidx] = vv; p[cidx] = vv;
  cf zz; zz.x = 0.f; zz.y = 0.f; xc[cidx] = zz;
  float partial = r0*r0 + r1*r1;
  for (int off = 32; off; off >>= 1) partial += __shfl_down(partial, off);
  const int l = tid & 63, wvid = tid >> 6;
  if (l == 0) wsum[wvid] = partial;
  __syncthreads();
  if (tid == 0) atomicAdd(&scL[b], wsum[0]+wsum[1]+wsum[2]+wsum[3]);
}

// ---------------- CG / FFT kernels ----------------
// scL (128 floats/layer): rtr[it*4+b] (it 0..9), pAp[40+it*4+b], ApAp[80+it*4+b].
// 3 dispatches/iter. rtr recurrence: rtr_new = a^2*ApAp - rtr (Hermitian A).

__global__ void __launch_bounds__(256) pass_a_k(const cf* __restrict__ rold, cf* __restrict__ rnew,
                                                const cf* __restrict__ pold, cf* __restrict__ pnew,
                                                cf* __restrict__ xc, const cf* __restrict__ Ap,
                                                const cf* __restrict__ csm, cf* __restrict__ t,
                                                float* __restrict__ scL, int it) {
  __shared__ cf rowbuf[4][434];
  const int l = threadIdx.x & 63, wv = threadIdx.x >> 6;
  const int y = blockIdx.x * 4 + wv;
  const int c = blockIdx.y, b = blockIdx.z;
  const int rowoff = b*HW + y*WW;
  cf pv[6];
  if (it == 0) {
    #pragma unroll
    for (int m = 0; m < 6; ++m) pv[m] = pold[rowoff + l + 64*m];
  } else {
    const float rtrp  = scL[(it-1)*4 + b];
    const float pApp  = scL[40 + (it-1)*4 + b];
    const float ApApp = scL[80 + (it-1)*4 + b];
    const float alpha = rtrp / pApp;
    const float rtrn  = alpha*alpha*ApApp - rtrp;
    const float beta  = rtrn / rtrp;
    if (blockIdx.x == 0 && c == 0 && threadIdx.x == 0) scL[it*4 + b] = rtrn;
    #pragma unroll
    for (int m = 0; m < 6; ++m) {
      const int idx = rowoff + l + 64*m;
      cf rv = rold[idx];
      cf av = Ap[idx];
      rv.x -= alpha*av.x; rv.y -= alpha*av.y;
      cf po = pold[idx];
      pv[m].x = rv.x + beta*po.x; pv[m].y = rv.y + beta*po.y;
      if (c == 0) {
        rnew[idx] = rv;
        pnew[idx] = pv[m];
        cf xv = xc[idx]; xv.x += alpha*po.x; xv.y += alpha*po.y; xc[idx] = xv;
      }
    }
  }
  const cf* crow = csm + (b*CC + c)*HW + y*WW;
  cf v[6];
  #pragma unroll
  for (int m = 0; m < 6; ++m) v[m] = cmul(crow[l + 64*m], pv[m]);
  cf uA[3], uB[3];
  fft384_wave<-1>(l, v, uA, uB);
  const int R3 = 3 * brev7(l);
  cf* rb = rowbuf[wv];                  // wave-private
  #pragma unroll
  for (int k1 = 0; k1 < 3; ++k1) { rb[padi(k1 + R3)] = uA[k1]; rb[padi(k1 + R3 + 3)] = uB[k1]; }
  cf* trow = t + (b*CC + c)*HW + y*WW;
  #pragma unroll
  for (int m = 0; m < 6; ++m) trow[l + 64*m] = rb[padi(l + 64*m)];
}

__global__ void __launch_bounds__(256) pass_b_k(cf* __restrict__ t, const float* __restrict__ mask) {
  __shared__ cf tile[431*9];
  const int b = blockIdx.z, c = blockIdx.y, x0 = blockIdx.x * 8;
  cf* base = t + (b*CC + c)*HW;
  for (int e = threadIdx.x; e < 3072; e += 256) {
    int y = e >> 3, xx = e & 7;
    tile[padi(y)*9 + xx] = base[y*WW + x0 + xx];
  }
  __syncthreads();
  const int l = threadIdx.x & 63, wv = threadIdx.x >> 6;
  const int R3 = 3 * brev7(l);
  for (int rep = 0; rep < 2; ++rep) {
    const int xx = wv*2 + rep, x = x0 + xx;
    cf v[6];
    #pragma unroll
    for (int m = 0; m < 6; ++m) v[m] = tile[padi(l + 64*m)*9 + xx];
    cf uA[3], uB[3];
    fft384_wave<-1>(l, v, uA, uB);
    const float* mrow = mask + b*HW + x;
    #pragma unroll
    for (int k1 = 0; k1 < 3; ++k1) {
      float mA = mrow[(k1 + R3)*WW], mB = mrow[(k1 + R3 + 3)*WW];
      uA[k1].x *= mA; uA[k1].y *= mA; uB[k1].x *= mB; uB[k1].y *= mB;
    }
    __syncthreads();
    #pragma unroll
    for (int k1 = 0; k1 < 3; ++k1) { tile[padi(k1 + R3)*9 + xx] = uA[k1]; tile[padi(k1 + R3 + 3)*9 + xx] = uB[k1]; }
    __syncthreads();
    #pragma unroll
    for (int m = 0; m < 6; ++m) v[m] = tile[padi(l + 64*m)*9 + xx];
    fft384_wave<1>(l, v, uA, uB);
    const float s = 1.0f / 384.0f;
    #pragma unroll
    for (int k1 = 0; k1 < 3; ++k1) {
      uA[k1].x *= s; uA[k1].y *= s; uB[k1].x *= s; uB[k1].y *= s;
      tile[padi(k1 + R3)*9 + xx] = uA[k1]; tile[padi(k1 + R3 + 3)*9 + xx] = uB[k1];
    }
    __syncthreads();
  }
  for (int e = threadIdx.x; e < 3072; e += 256) {
    int y = e >> 3, xx = e & 7;
    base[y*WW + x0 + xx] = tile[padi(y)*9 + xx];
  }
}

// pass_c: one y-row per block (HH x BB grid), 8 coils split 2/wave, LDS reduce.
__global__ void __launch_bounds__(256) pass_c_k(const cf* __restrict__ t, const cf* __restrict__ csm,
                                                const cf* __restrict__ p, cf* __restrict__ Ap,
                                                const float* __restrict__ lam,
                                                float* __restrict__ scL, int it) {
  __shared__ cf rowbuf[4][434];
  __shared__ cf redbuf[3][384];
  const int l = threadIdx.x & 63, wv = threadIdx.x >> 6;
  const int y = blockIdx.x, b = blockIdx.y;
  const int R3 = 3 * brev7(l);
  cf* rb = rowbuf[wv];                  // wave-private
  cf acc[6] = {};
  #pragma unroll 1
  for (int ci = 0; ci < 2; ++ci) {
    const int c = wv*2 + ci;
    const cf* trow = t + (b*CC + c)*HW + y*WW;
    cf v[6];
    #pragma unroll
    for (int m = 0; m < 6; ++m) v[m] = trow[l + 64*m];
    cf uA[3], uB[3];
    fft384_wave<1>(l, v, uA, uB);
    #pragma unroll
    for (int k1 = 0; k1 < 3; ++k1) { rb[padi(k1 + R3)] = uA[k1]; rb[padi(k1 + R3 + 3)] = uB[k1]; }
    const cf* crow = csm + (b*CC + c)*HW + y*WW;
    #pragma unroll
    for (int m = 0; m < 6; ++m) {
      cf cs = crow[l + 64*m];
      cf wz = rb[padi(l + 64*m)];
      acc[m].x += cs.x*wz.x + cs.y*wz.y;
      acc[m].y += cs.x*wz.y - cs.y*wz.x;
    }
  }
  if (wv > 0) {
    #pragma unroll
    for (int m = 0; m < 6; ++m) redbuf[wv - 1][l + 64*m] = acc[m];
  }
  __syncthreads();
  if (wv == 0) {
    #pragma unroll
    for (int m = 0; m < 6; ++m) {
      #pragma unroll
      for (int j = 0; j < 3; ++j) {
        cf o = redbuf[j][l + 64*m];
        acc[m].x += o.x; acc[m].y += o.y;
      }
    }
    const float lamv = lam[0];
    const float sc384 = 1.0f / 384.0f;
    const cf* prow = p + b*HW + y*WW;
    cf* aprow = Ap + b*HW + y*WW;
    float partial = 0.f, partial2 = 0.f;
    #pragma unroll
    for (int m = 0; m < 6; ++m) {
      cf pv = prow[l + 64*m];
      cf ap; ap.x = acc[m].x*sc384 + lamv*pv.x; ap.y = acc[m].y*sc384 + lamv*pv.y;
      aprow[l + 64*m] = ap;
      partial  += pv.x*ap.x + pv.y*ap.y;
      partial2 += ap.x*ap.x + ap.y*ap.y;
    }
    #pragma unroll
    for (int off = 32; off; off >>= 1) {
      partial  += __shfl_down(partial, off);
      partial2 += __shfl_down(partial2, off);
    }
    if (l == 0) {
      atomicAdd(&scL[40 + it*4 + b], partial);
      atomicAdd(&scL[80 + it*4 + b], partial2);
    }
  }
}

// final x = xc + alpha9 * p9, planar output
__global__ void __launch_bounds__(256) final_x_k(const cf* __restrict__ xc, const cf* __restrict__ p9,
                                                 const float* __restrict__ scL, float* __restrict__ out) {
  const int idx = blockIdx.x * 256 + threadIdx.x;
  const int b = idx / HW;
  const int rem = idx - b*HW;
  const float alpha = scL[(CGITERS-1)*4 + b] / scL[40 + (CGITERS-1)*4 + b];
  cf xv = xc[idx], pv = p9[idx];
  xv.x += alpha*pv.x; xv.y += alpha*pv.y;
  out[b*2*HW + rem] = xv.x;
  out[b*2*HW + HW + rem] = xv.y;
}

__global__ void zero_sc_k(float* sc) {
  for (int i = threadIdx.x; i < NLAYERS*128; i += 256) sc[i] = 0.f;
}

extern "C" void kernel_launch(void* const* d_in, const int* in_sizes, int n_in,
                              void* d_out, int out_size, void* d_ws, size_t ws_size,
                              hipStream_t stream) {
  (void)in_sizes; (void)n_in; (void)out_size; (void)ws_size;
  const float* under  = (const float*)d_in[0];
  const cf*    csm    = (const cf*)d_in[1];
  const float* mask   = (const float*)d_in[2];
  const float* lam    = (const float*)d_in[3];
  const float* w_in   = (const float*)d_in[4];
  const float* b_in   = (const float*)d_in[5];
  const float* ws_mid = (const float*)d_in[6];
  const float* bs_mid = (const float*)d_in[7];
  const float* w_out  = (const float*)d_in[8];
  const float* b_out  = (const float*)d_in[9];
  float* xcur = (float*)d_out;

  char* bws = (char*)d_ws;
  size_t off = 0;
  auto carve = [&](size_t bytes) { char* pp = bws + off; off += (bytes + 255) & ~(size_t)255; return (void*)pp; };
  __hip_bfloat16* actA = (__hip_bfloat16*)carve((size_t)BB*PP*64*2);
  __hip_bfloat16* actB = (__hip_bfloat16*)carve((size_t)BB*PP*64*2);
  cf* t     = (cf*)carve((size_t)BB*CC*HW*8);
  cf* rbuf0 = (cf*)carve((size_t)BB*HW*8);
  cf* rbuf1 = (cf*)carve((size_t)BB*HW*8);
  cf* pbuf0 = (cf*)carve((size_t)BB*HW*8);
  cf* pbuf1 = (cf*)carve((size_t)BB*HW*8);
  cf* xc    = (cf*)carve((size_t)BB*HW*8);
  cf* Ap    = (cf*)carve((size_t)BB*HW*8);
  float* sc = (float*)carve(4096);
  __hip_bfloat16* wrep = (__hip_bfloat16*)carve((size_t)7*9*64*64*2);

  hipMemcpyAsync(xcur, under, (size_t)BB*2*HW*sizeof(float), hipMemcpyDeviceToDevice, stream);

  zero_sc_k<<<1, 256, 0, stream>>>(sc);
  repack_mid_k<<<(7*9*64*64 + 255)/256, 256, 0, stream>>>(ws_mid, wrep);
  zero_guard_k<<<(2*BB*1540*8 + 255)/256, 256, 0, stream>>>(actA, actB);

  dim3 cgrid(WW/32, HH/8, BB);       // conv_in / conv_out (32x8 tiles)
  dim3 agrid(HH/4, CC, BB);
  dim3 bgrid(WW/8, CC, BB);
  dim3 c2grid(HH, BB);               // pass_c: one row per block
  const int egrid = BB*HW/256;

  __hip_bfloat16* bufs[2] = { actA, actB };
  cf* rb[2] = { rbuf0, rbuf1 };
  cf* pb[2] = { pbuf0, pbuf1 };

  for (int layer = 0; layer < NLAYERS; ++layer) {
    float* scL = sc + layer*128;
    conv_in_k<<<cgrid, 256, 0, stream>>>(xcur, w_in, b_in, bufs[0]);
    for (int i = 0; i < 7; ++i) {
      conv_mid_mfma_k<<<dim3(256), 512, 0, stream>>>(bufs[i & 1], wrep + (size_t)i*9*4096,
                                                     bs_mid + i*64, bufs[(i + 1) & 1], (i % 2 == 0) ? 1 : 0);
    }
    conv_out_k<<<cgrid, 256, 0, stream>>>(bufs[1], w_out, b_out, xcur, under, lam,
                                          rbuf0, pbuf0, xc, scL);
    for (int it = 0; it < CGITERS; ++it) {
      cf* rold = rb[(it + 1) & 1];
      cf* rnew = rb[it & 1];
      cf* pold = pb[(it + 1) & 1];
      cf* pnew = pb[it & 1];
      if (it == 0) { rold = rbuf0; pold = pbuf0; rnew = rbuf0; pnew = pbuf0; }
      pass_a_k<<<agrid, 256, 0, stream>>>(rold, rnew, pold, pnew, xc, Ap, csm, t, scL, it);
      pass_b_k<<<bgrid, 256, 0, stream>>>(t, mask);
      pass_c_k<<<c2grid, 256, 0, stream>>>(t, csm, pnew, Ap, lam, scL, it);
    }
    final_x_k<<<egrid, 256, 0, stream>>>(xc, pb[(CGITERS - 1) & 1], scL, xcur);
  }
}

// Round 5
// 9423.196 us; speedup vs baseline: 1.1524x; 1.0669x over previous
//
#include <hip/hip_runtime.h>
#include <hip/hip_bf16.h>
#include <math.h>

#define HH 384
#define WW 384
#define HW (HH*WW)
#define WP 386              // padded row stride (1-px guard ring)
#define PP (386*386)        // padded image pixels
#define BB 4
#define CC 8
#define NLAYERS 5
#define CGITERS 10
#define PI_F 3.14159265358979323846f

typedef __attribute__((ext_vector_type(8))) short short8;
typedef __attribute__((ext_vector_type(4))) float floatx4;

struct cf { float x, y; };
__device__ __forceinline__ cf cadd(cf a, cf b){ cf r; r.x=a.x+b.x; r.y=a.y+b.y; return r; }
__device__ __forceinline__ cf csub(cf a, cf b){ cf r; r.x=a.x-b.x; r.y=a.y-b.y; return r; }
__device__ __forceinline__ cf cmul(cf a, cf b){ cf r; r.x=a.x*b.x - a.y*b.y; r.y=a.x*b.y + a.y*b.x; return r; }
__device__ __forceinline__ cf csqr(cf a){ cf r; r.x = a.x*a.x - a.y*a.y; r.y = 2.f*a.x*a.y; return r; }
__device__ __forceinline__ cf shflxor(cf v, int m){ cf r; r.x = __shfl_xor(v.x, m); r.y = __shfl_xor(v.y, m); return r; }
__device__ __forceinline__ int brev7(int l){ return (int)(__brev((unsigned)l) >> 25); }
__device__ __forceinline__ int padi(int i){ return i + (i >> 3); }

__device__ __forceinline__ void radix3(cf a0, cf a1, cf a2, float s3, cf y[3]) {
  float tx = a1.x + a2.x, ty_ = a1.y + a2.y;
  float ux = a1.x - a2.x, uy = a1.y - a2.y;
  y[0].x = a0.x + tx;              y[0].y = a0.y + ty_;
  y[1].x = a0.x - 0.5f*tx - s3*uy; y[1].y = a0.y - 0.5f*ty_ + s3*ux;
  y[2].x = a0.x - 0.5f*tx + s3*uy; y[2].y = a0.y - 0.5f*ty_ - s3*ux;
}

// 384-point DFT across one 64-lane wave. SIGN=-1 fwd, +1 inverse (no 1/N scale).
template<int SIGN>
__device__ __forceinline__ void fft384_wave(int l, const cf v[6], cf uA[3], cf uB[3]) {
  const float s3 = SIGN * 0.8660254037844386f;
  radix3(v[0], v[2], v[4], s3, uA);
  radix3(v[1], v[3], v[5], s3, uB);
  float sA, cA;
  __sincosf(SIGN * (2.0f * PI_F / 384.0f) * (float)l, &sA, &cA);
  cf wA1; wA1.x = cA; wA1.y = sA;
  cf wA2 = csqr(wA1);
  cf w6; w6.x = 0.5f; w6.y = s3;            // exp(SIGN*i*pi/3)
  cf wB1 = cmul(wA1, w6);
  cf wB2 = csqr(wB1);
  uA[1] = cmul(uA[1], wA1); uA[2] = cmul(uA[2], wA2);
  uB[1] = cmul(uB[1], wB1); uB[2] = cmul(uB[2], wB2);
  cf u = cmul(wA2, wA1);                    // exp(SIGN*i*pi*l/64): stage h=64 twiddle
  #pragma unroll
  for (int k1 = 0; k1 < 3; ++k1) {
    cf a = uA[k1], b = uB[k1];
    uA[k1] = cadd(a, b);
    uB[k1] = cmul(csub(a, b), u);
  }
  #pragma unroll
  for (int h = 32; h >= 1; h >>= 1) {
    u = csqr(u);                             // exp(SIGN*i*pi*l/h)
    const bool up = (l & h) != 0;
    #pragma unroll
    for (int k1 = 0; k1 < 3; ++k1) {
      cf pa = shflxor(uA[k1], h);
      cf pb = shflxor(uB[k1], h);
      cf na = up ? cmul(csub(uA[k1], pa), u) : cadd(uA[k1], pa);
      cf nb = up ? cmul(csub(uB[k1], pb), u) : cadd(uB[k1], pb);
      uA[k1] = na; uB[k1] = nb;
    }
  }
}

// ---------------- conv kernels ----------------
// Activations in PADDED NHWC bf16: act[b][y+1][x+1][c], row stride WP=386,
// c=64 contiguous. 1-px guard ring zeroed once per launch; conv stores only
// write interior -> guards stay zero -> halo reads need NO bounds checks.

__global__ void repack_mid_k(const float* __restrict__ ws_mid, __hip_bfloat16* __restrict__ wrep) {
  const int idx = blockIdx.x * 256 + threadIdx.x;
  if (idx >= 7*9*64*64) return;
  const int ci = idx & 63, co = (idx >> 6) & 63, tap = (idx >> 12) % 9, i = idx / (9*4096);
  wrep[idx] = __float2bfloat16(ws_mid[(((size_t)i*64 + co)*64 + ci)*9 + tap]);
}

// zero the guard ring of both activation buffers (1540 px per image per buf)
__global__ void zero_guard_k(__hip_bfloat16* __restrict__ a, __hip_bfloat16* __restrict__ b2) {
  const int idx = blockIdx.x * 256 + threadIdx.x;
  if (idx >= 2*BB*1540*8) return;
  const int s = idx & 7; int rest = idx >> 3;
  const int px = rest % 1540; rest /= 1540;
  const int bb = rest & 3; const int buf = rest >> 2;
  int row, col;
  if (px < WP)        { row = 0;    col = px; }
  else if (px < 2*WP) { row = HH+1; col = px - WP; }
  else { const int k = px - 2*WP; row = 1 + (k >> 1); col = (k & 1) ? (WW+1) : 0; }
  __hip_bfloat16* base = buf ? b2 : a;
  *(uint4*)(base + ((size_t)bb*PP + (size_t)row*WP + col)*64 + s*8) = make_uint4(0u,0u,0u,0u);
}

__global__ void __launch_bounds__(256) conv_in_k(const float* __restrict__ xin,
                                                 const float* __restrict__ w,
                                                 const float* __restrict__ bias,
                                                 __hip_bfloat16* __restrict__ out) {
  __shared__ float tile[2][340];
  const int tx = threadIdx.x & 31, ty = threadIdx.x >> 5;
  const int x0 = blockIdx.x * 32, y0 = blockIdx.y * 8, b = blockIdx.z;
  for (int e = threadIdx.x; e < 680; e += 256) {
    int ci = e / 340, rr = e % 340;
    int iy = y0 - 1 + rr / 34, ix = x0 - 1 + rr % 34;
    float v = 0.f;
    if (iy >= 0 && iy < HH && ix >= 0 && ix < WW)
      v = xin[(b*2 + ci)*HW + iy*WW + ix];
    tile[ci][rr] = v;
  }
  __syncthreads();
  float acc[64];
  #pragma unroll
  for (int co = 0; co < 64; ++co) acc[co] = bias[co];
  #pragma unroll
  for (int ci = 0; ci < 2; ++ci) {
    float v0 = tile[ci][ty*34+tx],     v1 = tile[ci][ty*34+tx+1],     v2 = tile[ci][ty*34+tx+2];
    float v3 = tile[ci][(ty+1)*34+tx], v4 = tile[ci][(ty+1)*34+tx+1], v5 = tile[ci][(ty+1)*34+tx+2];
    float v6 = tile[ci][(ty+2)*34+tx], v7 = tile[ci][(ty+2)*34+tx+1], v8 = tile[ci][(ty+2)*34+tx+2];
    #pragma unroll
    for (int co = 0; co < 64; ++co) {
      const float* wp = w + co*18 + ci*9;
      float a = acc[co];
      a = fmaf(v0, wp[0], a); a = fmaf(v1, wp[1], a); a = fmaf(v2, wp[2], a);
      a = fmaf(v3, wp[3], a); a = fmaf(v4, wp[4], a); a = fmaf(v5, wp[5], a);
      a = fmaf(v6, wp[6], a); a = fmaf(v7, wp[7], a); a = fmaf(v8, wp[8], a);
      acc[co] = a;
    }
  }
  const size_t obase = ((size_t)b*PP + (size_t)(y0 + ty + 1)*WP + (x0 + tx + 1))*64;
  #pragma unroll
  for (int s = 0; s < 8; ++s) {
    uint4 u;
    __hip_bfloat16* hp = (__hip_bfloat16*)&u;
    #pragma unroll
    for (int j = 0; j < 8; ++j) hp[j] = __float2bfloat16(acc[s*8 + j]);
    *(uint4*)(out + obase + s*8) = u;
  }
}

// MFMA implicit-GEMM mid conv, v6 = r2 structure (best measured, 107.6us) on
// the padded layout:
// - 256 thr / 4 waves, 32x8 tile, 2 blocks/CU co-resident (register-limited;
//   the r4 persistent/1-block variant lost the inter-block overlap: 128us).
// - branch-free global_load_lds DMA staging for ALL blocks (padded halo).
// - rolled tap loop + one-tap-ahead weight dbuf (full unroll spills: r1).
// - both-sides XOR channel-group swizzle (bank conflicts 2.95M -> 0.3M).
__global__ void __launch_bounds__(256) conv_mid_mfma_k(
    const __hip_bfloat16* __restrict__ in,    // padded NHWC
    const __hip_bfloat16* __restrict__ wrep,  // [9][64][64] bf16
    const float* __restrict__ bias,
    __hip_bfloat16* __restrict__ out, int relu) {
  __shared__ __align__(16) __hip_bfloat16 atile[2752*8];  // 44032 B (32 pad slots)
  const int tid = threadIdx.x;
  const int l = tid & 63, wv = tid >> 6;
  const int x0 = blockIdx.x * 32, y0 = blockIdx.y * 8, b = blockIdx.z;

  const int kseg = l >> 4;
  const int lr = l & 15;

  // weight prefetch for tap 0 (L2-resident, issued before staging drain)
  const __hip_bfloat16* wlane = wrep + lr*64 + kseg*8;
  short8 bf[4][2];
  #pragma unroll
  for (int nt = 0; nt < 4; ++nt) {
    bf[nt][0] = *(const short8*)(wlane + nt*1024);
    bf[nt][1] = *(const short8*)(wlane + nt*1024 + 32);
  }

  // ---- stage A-tile: 340 px * 8 slots = 2720 16B slots, DMA path.
  // slot (p, s) <- channel-group s^(p&7) of halo pixel p (XOR swizzle).
  const __hip_bfloat16* inb = in + (size_t)b*PP*64;
  #pragma unroll
  for (int i = 0; i < 10; ++i) {
    const int j = i*256 + tid;
    const int p = j >> 3, s = j & 7;
    const int g = s ^ (p & 7);
    const __hip_bfloat16* src = inb + ((size_t)(y0 + p/34)*WP + (x0 + p%34))*64 + g*8;
    __builtin_amdgcn_global_load_lds(
        (const __attribute__((address_space(1))) void*)src,
        (__attribute__((address_space(3))) void*)(atile + (i*256 + wv*64)*8),
        16, 0, 0);
  }
  if (tid < 160) {                             // tail slots 2560..2719
    const int j = 2560 + tid;
    const int p = j >> 3, s = j & 7;
    const int g = s ^ (p & 7);
    uint4 v = *(const uint4*)(inb + ((size_t)(y0 + p/34)*WP + (x0 + p%34))*64 + g*8);
    *(uint4*)(atile + j*8) = v;
  }

  floatx4 acc[4][4];
  #pragma unroll
  for (int mt = 0; mt < 4; ++mt)
    #pragma unroll
    for (int nt = 0; nt < 4; ++nt)
      acc[mt][nt] = (floatx4){0.f, 0.f, 0.f, 0.f};

  __syncthreads();

  #pragma unroll 1
  for (int tap = 0; tap < 9; ++tap) {
    short8 bfn[4][2];
    if (tap < 8) {
      const __hip_bfloat16* wn = wlane + (tap + 1)*4096;
      #pragma unroll
      for (int nt = 0; nt < 4; ++nt) {
        bfn[nt][0] = *(const short8*)(wn + nt*1024);
        bfn[nt][1] = *(const short8*)(wn + nt*1024 + 32);
      }
    }
    const int dy = tap / 3, dx = tap - dy*3;
    short8 af[4][2];
    #pragma unroll
    for (int mt = 0; mt < 4; ++mt) {
      const int ry = 2*wv + (mt >> 1) + dy;
      const int px = (mt & 1)*16 + lr + dx;
      const int p  = ry*34 + px;
      const int eo = p*64 + ((kseg ^ (p & 7)) << 3);   // swizzled elem offset
      af[mt][0] = *(const short8*)(atile + eo);
      af[mt][1] = *(const short8*)(atile + (eo ^ 32)); // (kseg+4)^(p&7) slot
    }
    #pragma unroll
    for (int mt = 0; mt < 4; ++mt)
      #pragma unroll
      for (int nt = 0; nt < 4; ++nt) {
        acc[mt][nt] = __builtin_amdgcn_mfma_f32_16x16x32_bf16(af[mt][0], bf[nt][0], acc[mt][nt], 0, 0, 0);
        acc[mt][nt] = __builtin_amdgcn_mfma_f32_16x16x32_bf16(af[mt][1], bf[nt][1], acc[mt][nt], 0, 0, 0);
      }
    if (tap < 8) {
      #pragma unroll
      for (int nt = 0; nt < 4; ++nt) { bf[nt][0] = bfn[nt][0]; bf[nt][1] = bfn[nt][1]; }
    }
  }

  // LDS-transpose epilogue -> coalesced 16B stores (reuses atile as [256][72])
  __syncthreads();
  __hip_bfloat16* otile = atile;
  #pragma unroll
  for (int mt = 0; mt < 4; ++mt) {
    const int row = 2*wv + (mt >> 1);
    #pragma unroll
    for (int nt = 0; nt < 4; ++nt) {
      const int ch = nt*16 + lr;
      const float bv = bias[ch];
      #pragma unroll
      for (int rr = 0; rr < 4; ++rr) {
        const int px = (mt & 1)*16 + kseg*4 + rr;
        float v = acc[mt][nt][rr] + bv;
        if (relu) v = fmaxf(v, 0.f);
        otile[(row*32 + px)*72 + ch] = __float2bfloat16(v);
      }
    }
  }
  __syncthreads();
  #pragma unroll
  for (int iter = 0; iter < 8; ++iter) {
    const int p = iter*32 + (tid >> 3), s = tid & 7;
    const int row = p >> 5, px = p & 31;
    uint4 v = *(const uint4*)(&otile[p*72 + s*8]);
    *(uint4*)(out + ((size_t)b*PP + (size_t)(y0 + row + 1)*WP + (x0 + px + 1))*64 + s*8) = v;
  }
}

// conv_out (co=2) + CG init, LDS-staged (padded input -> no bounds checks)
__global__ void __launch_bounds__(256) conv_out_k(const __hip_bfloat16* __restrict__ in,
                                                  const float* __restrict__ w,
                                                  const float* __restrict__ bias,
                                                  const float* __restrict__ xcur,
                                                  const float* __restrict__ under,
                                                  const float* __restrict__ lam,
                                                  cf* __restrict__ r, cf* __restrict__ p,
                                                  cf* __restrict__ xc, float* __restrict__ scL) {
  __shared__ __hip_bfloat16 atile[340*72];
  __shared__ float wl[2*64*9];
  __shared__ float wsum[4];
  const int tid = threadIdx.x;
  const int tx = tid & 31, ty = tid >> 5;
  const int x0 = blockIdx.x * 32, y0 = blockIdx.y * 8, b = blockIdx.z;

  for (int e = tid; e < 340*8; e += 256) {
    int pp = e >> 3, s = e & 7;
    uint4 v = *(const uint4*)(in + ((size_t)b*PP + (size_t)(y0 + pp/34)*WP + (x0 + pp%34))*64 + s*8);
    *(uint4*)(&atile[pp*72 + s*8]) = v;
  }
  for (int e = tid; e < 2*64*9; e += 256) wl[e] = w[e];
  __syncthreads();

  float a0 = bias[0], a1 = bias[1];
  #pragma unroll 1
  for (int tap = 0; tap < 9; ++tap) {
    const int dy = tap / 3, dx = tap - dy*3;
    const __hip_bfloat16* ap = &atile[((ty + dy)*34 + tx + dx)*72];
    #pragma unroll
    for (int s = 0; s < 8; ++s) {
      short8 v8 = *(const short8*)(ap + s*8);
      const __hip_bfloat16* hv = (const __hip_bfloat16*)&v8;
      #pragma unroll
      for (int j = 0; j < 8; ++j) {
        const float f = __bfloat162float(hv[j]);
        a0 = fmaf(f, wl[(s*8 + j)*9 + tap], a0);
        a1 = fmaf(f, wl[(64 + s*8 + j)*9 + tap], a1);
      }
    }
  }
  const float lamv = lam[0];
  const int y = y0 + ty, x = x0 + tx;
  const int idx2 = y*WW + x;
  float xv0 = xcur[b*2*HW + idx2],  xv1 = xcur[b*2*HW + HW + idx2];
  float u0  = under[b*2*HW + idx2], u1  = under[b*2*HW + HW + idx2];
  float r0 = u0 + lamv * (xv0 + a0);
  float r1 = u1 + lamv * (xv1 + a1);
  const int cidx = b*HW + idx2;
  cf vv; vv.x = r0; vv.y = r1;
  r[cidx] = vv; p[cidx] = vv;
  cf zz; zz.x = 0.f; zz.y = 0.f; xc[cidx] = zz;
  float partial = r0*r0 + r1*r1;
  for (int off = 32; off; off >>= 1) partial += __shfl_down(partial, off);
  const int l = tid & 63, wvid = tid >> 6;
  if (l == 0) wsum[wvid] = partial;
  __syncthreads();
  if (tid == 0) atomicAdd(&scL[b], wsum[0]+wsum[1]+wsum[2]+wsum[3]);
}

// ---------------- CG / FFT kernels ----------------
// scL (128 floats/layer): rtr[it*4+b] (it 0..9), pAp[40+it*4+b], ApAp[80+it*4+b].
// rtr recurrence: rtr_new = a^2*ApAp - rtr (Hermitian A).
// Per iter (it>0): update_k (x/r/p scalar update, ONCE — was redundantly done
// by all 8 coil-blocks in pass_a), then pass_a (row FFT), pass_b (col FFT +
// mask + inv col FFT), pass_c (inv row FFT + coil reduce + dots).

__global__ void __launch_bounds__(256) update_k(const cf* __restrict__ rold, cf* __restrict__ rnew,
                                                const cf* __restrict__ pold, cf* __restrict__ pnew,
                                                cf* __restrict__ xc, const cf* __restrict__ Ap,
                                                float* __restrict__ scL, int it) {
  const int idx = blockIdx.x * 256 + threadIdx.x;
  const int b = idx / HW;
  const float rtrp  = scL[(it-1)*4 + b];
  const float pApp  = scL[40 + (it-1)*4 + b];
  const float ApApp = scL[80 + (it-1)*4 + b];
  const float alpha = rtrp / pApp;
  const float rtrn  = alpha*alpha*ApApp - rtrp;
  const float beta  = rtrn / rtrp;
  if ((idx - b*HW) == 0) scL[it*4 + b] = rtrn;
  cf rv = rold[idx];
  cf av = Ap[idx];
  rv.x -= alpha*av.x; rv.y -= alpha*av.y;
  cf po = pold[idx];
  cf pv; pv.x = rv.x + beta*po.x; pv.y = rv.y + beta*po.y;
  rnew[idx] = rv;
  pnew[idx] = pv;
  cf xv = xc[idx]; xv.x += alpha*po.x; xv.y += alpha*po.y; xc[idx] = xv;
}

// pass_a: row FFT of csm*p per coil. 4 rows/block (one per wave).
__global__ void __launch_bounds__(256) pass_a_k(const cf* __restrict__ pin,
                                                const cf* __restrict__ csm, cf* __restrict__ t) {
  __shared__ cf rowbuf[4][434];
  const int l = threadIdx.x & 63, wv = threadIdx.x >> 6;
  const int y = blockIdx.x * 4 + wv;
  const int c = blockIdx.y, b = blockIdx.z;
  const cf* prow = pin + b*HW + y*WW;
  const cf* crow = csm + (b*CC + c)*HW + y*WW;
  cf v[6];
  #pragma unroll
  for (int m = 0; m < 6; ++m) v[m] = cmul(crow[l + 64*m], prow[l + 64*m]);
  cf uA[3], uB[3];
  fft384_wave<-1>(l, v, uA, uB);
  const int R3 = 3 * brev7(l);
  cf* rb = rowbuf[wv];                  // wave-private
  #pragma unroll
  for (int k1 = 0; k1 < 3; ++k1) { rb[padi(k1 + R3)] = uA[k1]; rb[padi(k1 + R3 + 3)] = uB[k1]; }
  cf* trow = t + (b*CC + c)*HW + y*WW;
  #pragma unroll
  for (int m = 0; m < 6; ++m) trow[l + 64*m] = rb[padi(l + 64*m)];
}

__global__ void __launch_bounds__(256) pass_b_k(cf* __restrict__ t, const float* __restrict__ mask) {
  __shared__ cf tile[431*9];
  const int b = blockIdx.z, c = blockIdx.y, x0 = blockIdx.x * 8;
  cf* base = t + (b*CC + c)*HW;
  for (int e = threadIdx.x; e < 3072; e += 256) {
    int y = e >> 3, xx = e & 7;
    tile[padi(y)*9 + xx] = base[y*WW + x0 + xx];
  }
  __syncthreads();
  const int l = threadIdx.x & 63, wv = threadIdx.x >> 6;
  const int R3 = 3 * brev7(l);
  for (int rep = 0; rep < 2; ++rep) {
    const int xx = wv*2 + rep, x = x0 + xx;
    cf v[6];
    #pragma unroll
    for (int m = 0; m < 6; ++m) v[m] = tile[padi(l + 64*m)*9 + xx];
    cf uA[3], uB[3];
    fft384_wave<-1>(l, v, uA, uB);
    const float* mrow = mask + b*HW + x;
    #pragma unroll
    for (int k1 = 0; k1 < 3; ++k1) {
      float mA = mrow[(k1 + R3)*WW], mB = mrow[(k1 + R3 + 3)*WW];
      uA[k1].x *= mA; uA[k1].y *= mA; uB[k1].x *= mB; uB[k1].y *= mB;
    }
    __syncthreads();
    #pragma unroll
    for (int k1 = 0; k1 < 3; ++k1) { tile[padi(k1 + R3)*9 + xx] = uA[k1]; tile[padi(k1 + R3 + 3)*9 + xx] = uB[k1]; }
    __syncthreads();
    #pragma unroll
    for (int m = 0; m < 6; ++m) v[m] = tile[padi(l + 64*m)*9 + xx];
    fft384_wave<1>(l, v, uA, uB);
    const float s = 1.0f / 384.0f;
    #pragma unroll
    for (int k1 = 0; k1 < 3; ++k1) {
      uA[k1].x *= s; uA[k1].y *= s; uB[k1].x *= s; uB[k1].y *= s;
      tile[padi(k1 + R3)*9 + xx] = uA[k1]; tile[padi(k1 + R3 + 3)*9 + xx] = uB[k1];
    }
    __syncthreads();
  }
  for (int e = threadIdx.x; e < 3072; e += 256) {
    int y = e >> 3, xx = e & 7;
    base[y*WW + x0 + xx] = tile[padi(y)*9 + xx];
  }
}

// pass_c v2: one y-row per block (HH x BB grid), 8 coils split 2/wave with
// per-coil LDS double-buffer (loads of coil 2 overlap FFT of coil 1), then a
// FULLY PARALLEL tail: all 4 waves publish acc to redbuf, all 256 threads
// split the 384 columns (coalesced Ap write + p read), block-reduce the dots.
// (old version: wave 0 did the whole reduce/write/dot tail alone.)
__global__ void __launch_bounds__(256) pass_c_k(const cf* __restrict__ t, const cf* __restrict__ csm,
                                                const cf* __restrict__ p, cf* __restrict__ Ap,
                                                const float* __restrict__ lam,
                                                float* __restrict__ scL, int it) {
  __shared__ cf rowbuf[4][2][434];
  __shared__ cf redbuf[4][384];
  __shared__ float wsums[4][2];
  const int tid = threadIdx.x;
  const int l = tid & 63, wv = tid >> 6;
  const int y = blockIdx.x, b = blockIdx.y;
  const int R3 = 3 * brev7(l);
  cf acc[6] = {};
  #pragma unroll
  for (int ci = 0; ci < 2; ++ci) {
    const int c = wv*2 + ci;
    const cf* trow = t + (b*CC + c)*HW + y*WW;
    cf v[6];
    #pragma unroll
    for (int m = 0; m < 6; ++m) v[m] = trow[l + 64*m];
    cf uA[3], uB[3];
    fft384_wave<1>(l, v, uA, uB);
    cf* rb = rowbuf[wv][ci];            // wave-private, per-coil buffer
    #pragma unroll
    for (int k1 = 0; k1 < 3; ++k1) { rb[padi(k1 + R3)] = uA[k1]; rb[padi(k1 + R3 + 3)] = uB[k1]; }
    const cf* crow = csm + (b*CC + c)*HW + y*WW;
    #pragma unroll
    for (int m = 0; m < 6; ++m) {
      cf cs = crow[l + 64*m];
      cf wz = rb[padi(l + 64*m)];
      acc[m].x += cs.x*wz.x + cs.y*wz.y;
      acc[m].y += cs.x*wz.y - cs.y*wz.x;
    }
  }
  #pragma unroll
  for (int m = 0; m < 6; ++m) redbuf[wv][m*64 + l] = acc[m];
  __syncthreads();

  const float lamv = lam[0];
  const float sc384 = 1.0f / 384.0f;
  const cf* prow = p + b*HW + y*WW;
  cf* aprow = Ap + b*HW + y*WW;
  float partial = 0.f, partial2 = 0.f;
  #pragma unroll
  for (int rep = 0; rep < 2; ++rep) {
    const int pos = rep*256 + tid;
    if (pos < 384) {
      cf s0 = redbuf[0][pos], s1 = redbuf[1][pos], s2 = redbuf[2][pos], s3 = redbuf[3][pos];
      cf s; s.x = (s0.x + s1.x) + (s2.x + s3.x); s.y = (s0.y + s1.y) + (s2.y + s3.y);
      cf pv = prow[pos];
      cf ap; ap.x = s.x*sc384 + lamv*pv.x; ap.y = s.y*sc384 + lamv*pv.y;
      aprow[pos] = ap;
      partial  += pv.x*ap.x + pv.y*ap.y;
      partial2 += ap.x*ap.x + ap.y*ap.y;
    }
  }
  #pragma unroll
  for (int off = 32; off; off >>= 1) {
    partial  += __shfl_down(partial, off);
    partial2 += __shfl_down(partial2, off);
  }
  if (l == 0) { wsums[wv][0] = partial; wsums[wv][1] = partial2; }
  __syncthreads();
  if (tid == 0) {
    atomicAdd(&scL[40 + it*4 + b], (wsums[0][0]+wsums[1][0])+(wsums[2][0]+wsums[3][0]));
    atomicAdd(&scL[80 + it*4 + b], (wsums[0][1]+wsums[1][1])+(wsums[2][1]+wsums[3][1]));
  }
}

// final x = xc + alpha9 * p9, planar output
__global__ void __launch_bounds__(256) final_x_k(const cf* __restrict__ xc, const cf* __restrict__ p9,
                                                 const float* __restrict__ scL, float* __restrict__ out) {
  const int idx = blockIdx.x * 256 + threadIdx.x;
  const int b = idx / HW;
  const int rem = idx - b*HW;
  const float alpha = scL[(CGITERS-1)*4 + b] / scL[40 + (CGITERS-1)*4 + b];
  cf xv = xc[idx], pv = p9[idx];
  xv.x += alpha*pv.x; xv.y += alpha*pv.y;
  out[b*2*HW + rem] = xv.x;
  out[b*2*HW + HW + rem] = xv.y;
}

__global__ void zero_sc_k(float* sc) {
  for (int i = threadIdx.x; i < NLAYERS*128; i += 256) sc[i] = 0.f;
}

extern "C" void kernel_launch(void* const* d_in, const int* in_sizes, int n_in,
                              void* d_out, int out_size, void* d_ws, size_t ws_size,
                              hipStream_t stream) {
  (void)in_sizes; (void)n_in; (void)out_size; (void)ws_size;
  const float* under  = (const float*)d_in[0];
  const cf*    csm    = (const cf*)d_in[1];
  const float* mask   = (const float*)d_in[2];
  const float* lam    = (const float*)d_in[3];
  const float* w_in   = (const float*)d_in[4];
  const float* b_in   = (const float*)d_in[5];
  const float* ws_mid = (const float*)d_in[6];
  const float* bs_mid = (const float*)d_in[7];
  const float* w_out  = (const float*)d_in[8];
  const float* b_out  = (const float*)d_in[9];
  float* xcur = (float*)d_out;

  char* bws = (char*)d_ws;
  size_t off = 0;
  auto carve = [&](size_t bytes) { char* pp = bws + off; off += (bytes + 255) & ~(size_t)255; return (void*)pp; };
  __hip_bfloat16* actA = (__hip_bfloat16*)carve((size_t)BB*PP*64*2);
  __hip_bfloat16* actB = (__hip_bfloat16*)carve((size_t)BB*PP*64*2);
  cf* t     = (cf*)carve((size_t)BB*CC*HW*8);
  cf* rbuf0 = (cf*)carve((size_t)BB*HW*8);
  cf* rbuf1 = (cf*)carve((size_t)BB*HW*8);
  cf* pbuf0 = (cf*)carve((size_t)BB*HW*8);
  cf* pbuf1 = (cf*)carve((size_t)BB*HW*8);
  cf* xc    = (cf*)carve((size_t)BB*HW*8);
  cf* Ap    = (cf*)carve((size_t)BB*HW*8);
  float* sc = (float*)carve(4096);
  __hip_bfloat16* wrep = (__hip_bfloat16*)carve((size_t)7*9*64*64*2);

  hipMemcpyAsync(xcur, under, (size_t)BB*2*HW*sizeof(float), hipMemcpyDeviceToDevice, stream);

  zero_sc_k<<<1, 256, 0, stream>>>(sc);
  repack_mid_k<<<(7*9*64*64 + 255)/256, 256, 0, stream>>>(ws_mid, wrep);
  zero_guard_k<<<(2*BB*1540*8 + 255)/256, 256, 0, stream>>>(actA, actB);

  dim3 cgrid(WW/32, HH/8, BB);       // conv_in / conv_mid / conv_out (32x8 tiles)
  dim3 agrid(HH/4, CC, BB);
  dim3 bgrid(WW/8, CC, BB);
  dim3 c2grid(HH, BB);               // pass_c: one row per block
  const int egrid = BB*HW/256;

  __hip_bfloat16* bufs[2] = { actA, actB };
  cf* rb[2] = { rbuf0, rbuf1 };
  cf* pb[2] = { pbuf0, pbuf1 };

  for (int layer = 0; layer < NLAYERS; ++layer) {
    float* scL = sc + layer*128;
    conv_in_k<<<cgrid, 256, 0, stream>>>(xcur, w_in, b_in, bufs[0]);
    for (int i = 0; i < 7; ++i) {
      conv_mid_mfma_k<<<cgrid, 256, 0, stream>>>(bufs[i & 1], wrep + (size_t)i*9*4096,
                                                 bs_mid + i*64, bufs[(i + 1) & 1], (i % 2 == 0) ? 1 : 0);
    }
    conv_out_k<<<cgrid, 256, 0, stream>>>(bufs[1], w_out, b_out, xcur, under, lam,
                                          rbuf0, pbuf0, xc, scL);
    for (int it = 0; it < CGITERS; ++it) {
      cf* rold = rb[(it + 1) & 1];
      cf* rnew = rb[it & 1];
      cf* pold = pb[(it + 1) & 1];
      cf* pnew = pb[it & 1];
      if (it == 0) { rold = rbuf0; pold = pbuf0; rnew = rbuf0; pnew = pbuf0; }
      if (it > 0)
        update_k<<<egrid, 256, 0, stream>>>(rold, rnew, pold, pnew, xc, Ap, scL, it);
      pass_a_k<<<agrid, 256, 0, stream>>>(pnew, csm, t);
      pass_b_k<<<bgrid, 256, 0, stream>>>(t, mask);
      pass_c_k<<<c2grid, 256, 0, stream>>>(t, csm, pnew, Ap, lam, scL, it);
    }
    final_x_k<<<egrid, 256, 0, stream>>>(xc, pb[(CGITERS - 1) & 1], scL, xcur);
  }
}

// Round 6
// 8977.541 us; speedup vs baseline: 1.2096x; 1.0496x over previous
//
#include <hip/hip_runtime.h>
#include <hip/hip_bf16.h>
#include <hip/hip_fp16.h>
#include <math.h>

#define HH 384
#define WW 384
#define HW (HH*WW)
#define WP 386              // padded row stride (1-px guard ring)
#define PP (386*386)        // padded image pixels
#define BB 4
#define CC 8
#define NLAYERS 5
#define CGITERS 10
#define PI_F 3.14159265358979323846f

typedef __attribute__((ext_vector_type(8))) short short8;
typedef __attribute__((ext_vector_type(4))) float floatx4;

struct cf { float x, y; };
__device__ __forceinline__ cf cadd(cf a, cf b){ cf r; r.x=a.x+b.x; r.y=a.y+b.y; return r; }
__device__ __forceinline__ cf csub(cf a, cf b){ cf r; r.x=a.x-b.x; r.y=a.y-b.y; return r; }
__device__ __forceinline__ cf cmul(cf a, cf b){ cf r; r.x=a.x*b.x - a.y*b.y; r.y=a.x*b.y + a.y*b.x; return r; }
__device__ __forceinline__ cf csqr(cf a){ cf r; r.x = a.x*a.x - a.y*a.y; r.y = 2.f*a.x*a.y; return r; }
__device__ __forceinline__ cf shflxor(cf v, int m){ cf r; r.x = __shfl_xor(v.x, m); r.y = __shfl_xor(v.y, m); return r; }
__device__ __forceinline__ int brev7(int l){ return (int)(__brev((unsigned)l) >> 25); }
__device__ __forceinline__ int padi(int i){ return i + (i >> 3); }

// t-array storage: packed fp16 pair (4B/complex). Arithmetic stays fp32;
// fp16 rel-err 0.05% (vs bf16 0.4%); clamp guards the 65504 range edge.
__device__ __forceinline__ unsigned packh(cf v) {
  __half hx = __float2half(fminf(fmaxf(v.x, -60000.f), 60000.f));
  __half hy = __float2half(fminf(fmaxf(v.y, -60000.f), 60000.f));
  unsigned short ux = *(unsigned short*)&hx, uy = *(unsigned short*)&hy;
  return (unsigned)ux | ((unsigned)uy << 16);
}
__device__ __forceinline__ cf unpackh(unsigned u) {
  unsigned short ux = (unsigned short)(u & 0xffffu), uy = (unsigned short)(u >> 16);
  __half hx = *(__half*)&ux, hy = *(__half*)&uy;
  cf r; r.x = __half2float(hx); r.y = __half2float(hy); return r;
}

__device__ __forceinline__ void radix3(cf a0, cf a1, cf a2, float s3, cf y[3]) {
  float tx = a1.x + a2.x, ty_ = a1.y + a2.y;
  float ux = a1.x - a2.x, uy = a1.y - a2.y;
  y[0].x = a0.x + tx;              y[0].y = a0.y + ty_;
  y[1].x = a0.x - 0.5f*tx - s3*uy; y[1].y = a0.y - 0.5f*ty_ + s3*ux;
  y[2].x = a0.x - 0.5f*tx + s3*uy; y[2].y = a0.y - 0.5f*ty_ - s3*ux;
}

// 384-point DFT across one 64-lane wave. SIGN=-1 fwd, +1 inverse (no 1/N scale).
template<int SIGN>
__device__ __forceinline__ void fft384_wave(int l, const cf v[6], cf uA[3], cf uB[3]) {
  const float s3 = SIGN * 0.8660254037844386f;
  radix3(v[0], v[2], v[4], s3, uA);
  radix3(v[1], v[3], v[5], s3, uB);
  float sA, cA;
  __sincosf(SIGN * (2.0f * PI_F / 384.0f) * (float)l, &sA, &cA);
  cf wA1; wA1.x = cA; wA1.y = sA;
  cf wA2 = csqr(wA1);
  cf w6; w6.x = 0.5f; w6.y = s3;            // exp(SIGN*i*pi/3)
  cf wB1 = cmul(wA1, w6);
  cf wB2 = csqr(wB1);
  uA[1] = cmul(uA[1], wA1); uA[2] = cmul(uA[2], wA2);
  uB[1] = cmul(uB[1], wB1); uB[2] = cmul(uB[2], wB2);
  cf u = cmul(wA2, wA1);                    // exp(SIGN*i*pi*l/64): stage h=64 twiddle
  #pragma unroll
  for (int k1 = 0; k1 < 3; ++k1) {
    cf a = uA[k1], b = uB[k1];
    uA[k1] = cadd(a, b);
    uB[k1] = cmul(csub(a, b), u);
  }
  #pragma unroll
  for (int h = 32; h >= 1; h >>= 1) {
    u = csqr(u);                             // exp(SIGN*i*pi*l/h)
    const bool up = (l & h) != 0;
    #pragma unroll
    for (int k1 = 0; k1 < 3; ++k1) {
      cf pa = shflxor(uA[k1], h);
      cf pb = shflxor(uB[k1], h);
      cf na = up ? cmul(csub(uA[k1], pa), u) : cadd(uA[k1], pa);
      cf nb = up ? cmul(csub(uB[k1], pb), u) : cadd(uB[k1], pb);
      uA[k1] = na; uB[k1] = nb;
    }
  }
}

// ---------------- conv kernels ----------------
// Activations in PADDED NHWC bf16: act[b][y+1][x+1][c], row stride WP=386,
// c=64 contiguous. 1-px guard ring zeroed once per launch; conv stores only
// write interior -> guards stay zero -> halo reads need NO bounds checks.

__global__ void repack_mid_k(const float* __restrict__ ws_mid, __hip_bfloat16* __restrict__ wrep) {
  const int idx = blockIdx.x * 256 + threadIdx.x;
  if (idx >= 7*9*64*64) return;
  const int ci = idx & 63, co = (idx >> 6) & 63, tap = (idx >> 12) % 9, i = idx / (9*4096);
  wrep[idx] = __float2bfloat16(ws_mid[(((size_t)i*64 + co)*64 + ci)*9 + tap]);
}

// zero the guard ring of both activation buffers (1540 px per image per buf)
__global__ void zero_guard_k(__hip_bfloat16* __restrict__ a, __hip_bfloat16* __restrict__ b2) {
  const int idx = blockIdx.x * 256 + threadIdx.x;
  if (idx >= 2*BB*1540*8) return;
  const int s = idx & 7; int rest = idx >> 3;
  const int px = rest % 1540; rest /= 1540;
  const int bb = rest & 3; const int buf = rest >> 2;
  int row, col;
  if (px < WP)        { row = 0;    col = px; }
  else if (px < 2*WP) { row = HH+1; col = px - WP; }
  else { const int k = px - 2*WP; row = 1 + (k >> 1); col = (k & 1) ? (WW+1) : 0; }
  __hip_bfloat16* base = buf ? b2 : a;
  *(uint4*)(base + ((size_t)bb*PP + (size_t)row*WP + col)*64 + s*8) = make_uint4(0u,0u,0u,0u);
}

__global__ void __launch_bounds__(256) conv_in_k(const float* __restrict__ xin,
                                                 const float* __restrict__ w,
                                                 const float* __restrict__ bias,
                                                 __hip_bfloat16* __restrict__ out) {
  __shared__ float tile[2][340];
  const int tx = threadIdx.x & 31, ty = threadIdx.x >> 5;
  const int x0 = blockIdx.x * 32, y0 = blockIdx.y * 8, b = blockIdx.z;
  for (int e = threadIdx.x; e < 680; e += 256) {
    int ci = e / 340, rr = e % 340;
    int iy = y0 - 1 + rr / 34, ix = x0 - 1 + rr % 34;
    float v = 0.f;
    if (iy >= 0 && iy < HH && ix >= 0 && ix < WW)
      v = xin[(b*2 + ci)*HW + iy*WW + ix];
    tile[ci][rr] = v;
  }
  __syncthreads();
  float acc[64];
  #pragma unroll
  for (int co = 0; co < 64; ++co) acc[co] = bias[co];
  #pragma unroll
  for (int ci = 0; ci < 2; ++ci) {
    float v0 = tile[ci][ty*34+tx],     v1 = tile[ci][ty*34+tx+1],     v2 = tile[ci][ty*34+tx+2];
    float v3 = tile[ci][(ty+1)*34+tx], v4 = tile[ci][(ty+1)*34+tx+1], v5 = tile[ci][(ty+1)*34+tx+2];
    float v6 = tile[ci][(ty+2)*34+tx], v7 = tile[ci][(ty+2)*34+tx+1], v8 = tile[ci][(ty+2)*34+tx+2];
    #pragma unroll
    for (int co = 0; co < 64; ++co) {
      const float* wp = w + co*18 + ci*9;
      float a = acc[co];
      a = fmaf(v0, wp[0], a); a = fmaf(v1, wp[1], a); a = fmaf(v2, wp[2], a);
      a = fmaf(v3, wp[3], a); a = fmaf(v4, wp[4], a); a = fmaf(v5, wp[5], a);
      a = fmaf(v6, wp[6], a); a = fmaf(v7, wp[7], a); a = fmaf(v8, wp[8], a);
      acc[co] = a;
    }
  }
  const size_t obase = ((size_t)b*PP + (size_t)(y0 + ty + 1)*WP + (x0 + tx + 1))*64;
  #pragma unroll
  for (int s = 0; s < 8; ++s) {
    uint4 u;
    __hip_bfloat16* hp = (__hip_bfloat16*)&u;
    #pragma unroll
    for (int j = 0; j < 8; ++j) hp[j] = __float2bfloat16(acc[s*8 + j]);
    *(uint4*)(out + obase + s*8) = u;
  }
}

// MFMA implicit-GEMM mid conv (r2 structure, best measured 107.6us, padded):
// - 256 thr / 4 waves, 32x8 tile, 2 blocks/CU co-resident (register-limited;
//   persistent/1-block variant lost inter-block overlap: 128us).
// - branch-free global_load_lds DMA staging for ALL blocks (padded halo).
// - rolled tap loop + one-tap-ahead weight dbuf (full unroll spills).
// - both-sides XOR channel-group swizzle (bank conflicts 2.95M -> 0.3M).
__global__ void __launch_bounds__(256) conv_mid_mfma_k(
    const __hip_bfloat16* __restrict__ in,    // padded NHWC
    const __hip_bfloat16* __restrict__ wrep,  // [9][64][64] bf16
    const float* __restrict__ bias,
    __hip_bfloat16* __restrict__ out, int relu) {
  __shared__ __align__(16) __hip_bfloat16 atile[2752*8];  // 44032 B (32 pad slots)
  const int tid = threadIdx.x;
  const int l = tid & 63, wv = tid >> 6;
  const int x0 = blockIdx.x * 32, y0 = blockIdx.y * 8, b = blockIdx.z;

  const int kseg = l >> 4;
  const int lr = l & 15;

  // weight prefetch for tap 0 (L2-resident, issued before staging drain)
  const __hip_bfloat16* wlane = wrep + lr*64 + kseg*8;
  short8 bf[4][2];
  #pragma unroll
  for (int nt = 0; nt < 4; ++nt) {
    bf[nt][0] = *(const short8*)(wlane + nt*1024);
    bf[nt][1] = *(const short8*)(wlane + nt*1024 + 32);
  }

  // ---- stage A-tile: 340 px * 8 slots = 2720 16B slots, DMA path.
  // slot (p, s) <- channel-group s^(p&7) of halo pixel p (XOR swizzle).
  const __hip_bfloat16* inb = in + (size_t)b*PP*64;
  #pragma unroll
  for (int i = 0; i < 10; ++i) {
    const int j = i*256 + tid;
    const int p = j >> 3, s = j & 7;
    const int g = s ^ (p & 7);
    const __hip_bfloat16* src = inb + ((size_t)(y0 + p/34)*WP + (x0 + p%34))*64 + g*8;
    __builtin_amdgcn_global_load_lds(
        (const __attribute__((address_space(1))) void*)src,
        (__attribute__((address_space(3))) void*)(atile + (i*256 + wv*64)*8),
        16, 0, 0);
  }
  if (tid < 160) {                             // tail slots 2560..2719
    const int j = 2560 + tid;
    const int p = j >> 3, s = j & 7;
    const int g = s ^ (p & 7);
    uint4 v = *(const uint4*)(inb + ((size_t)(y0 + p/34)*WP + (x0 + p%34))*64 + g*8);
    *(uint4*)(atile + j*8) = v;
  }

  floatx4 acc[4][4];
  #pragma unroll
  for (int mt = 0; mt < 4; ++mt)
    #pragma unroll
    for (int nt = 0; nt < 4; ++nt)
      acc[mt][nt] = (floatx4){0.f, 0.f, 0.f, 0.f};

  __syncthreads();

  #pragma unroll 1
  for (int tap = 0; tap < 9; ++tap) {
    short8 bfn[4][2];
    if (tap < 8) {
      const __hip_bfloat16* wn = wlane + (tap + 1)*4096;
      #pragma unroll
      for (int nt = 0; nt < 4; ++nt) {
        bfn[nt][0] = *(const short8*)(wn + nt*1024);
        bfn[nt][1] = *(const short8*)(wn + nt*1024 + 32);
      }
    }
    const int dy = tap / 3, dx = tap - dy*3;
    short8 af[4][2];
    #pragma unroll
    for (int mt = 0; mt < 4; ++mt) {
      const int ry = 2*wv + (mt >> 1) + dy;
      const int px = (mt & 1)*16 + lr + dx;
      const int p  = ry*34 + px;
      const int eo = p*64 + ((kseg ^ (p & 7)) << 3);   // swizzled elem offset
      af[mt][0] = *(const short8*)(atile + eo);
      af[mt][1] = *(const short8*)(atile + (eo ^ 32)); // (kseg+4)^(p&7) slot
    }
    #pragma unroll
    for (int mt = 0; mt < 4; ++mt)
      #pragma unroll
      for (int nt = 0; nt < 4; ++nt) {
        acc[mt][nt] = __builtin_amdgcn_mfma_f32_16x16x32_bf16(af[mt][0], bf[nt][0], acc[mt][nt], 0, 0, 0);
        acc[mt][nt] = __builtin_amdgcn_mfma_f32_16x16x32_bf16(af[mt][1], bf[nt][1], acc[mt][nt], 0, 0, 0);
      }
    if (tap < 8) {
      #pragma unroll
      for (int nt = 0; nt < 4; ++nt) { bf[nt][0] = bfn[nt][0]; bf[nt][1] = bfn[nt][1]; }
    }
  }

  // LDS-transpose epilogue -> coalesced 16B stores (reuses atile as [256][72])
  __syncthreads();
  __hip_bfloat16* otile = atile;
  #pragma unroll
  for (int mt = 0; mt < 4; ++mt) {
    const int row = 2*wv + (mt >> 1);
    #pragma unroll
    for (int nt = 0; nt < 4; ++nt) {
      const int ch = nt*16 + lr;
      const float bv = bias[ch];
      #pragma unroll
      for (int rr = 0; rr < 4; ++rr) {
        const int px = (mt & 1)*16 + kseg*4 + rr;
        float v = acc[mt][nt][rr] + bv;
        if (relu) v = fmaxf(v, 0.f);
        otile[(row*32 + px)*72 + ch] = __float2bfloat16(v);
      }
    }
  }
  __syncthreads();
  #pragma unroll
  for (int iter = 0; iter < 8; ++iter) {
    const int p = iter*32 + (tid >> 3), s = tid & 7;
    const int row = p >> 5, px = p & 31;
    uint4 v = *(const uint4*)(&otile[p*72 + s*8]);
    *(uint4*)(out + ((size_t)b*PP + (size_t)(y0 + row + 1)*WP + (x0 + px + 1))*64 + s*8) = v;
  }
}

// conv_out (co=2) + CG init, LDS-staged (padded input -> no bounds checks)
__global__ void __launch_bounds__(256) conv_out_k(const __hip_bfloat16* __restrict__ in,
                                                  const float* __restrict__ w,
                                                  const float* __restrict__ bias,
                                                  const float* __restrict__ xcur,
                                                  const float* __restrict__ under,
                                                  const float* __restrict__ lam,
                                                  cf* __restrict__ r, cf* __restrict__ p,
                                                  cf* __restrict__ xc, float* __restrict__ scL) {
  __shared__ __hip_bfloat16 atile[340*72];
  __shared__ float wl[2*64*9];
  __shared__ float wsum[4];
  const int tid = threadIdx.x;
  const int tx = tid & 31, ty = tid >> 5;
  const int x0 = blockIdx.x * 32, y0 = blockIdx.y * 8, b = blockIdx.z;

  for (int e = tid; e < 340*8; e += 256) {
    int pp = e >> 3, s = e & 7;
    uint4 v = *(const uint4*)(in + ((size_t)b*PP + (size_t)(y0 + pp/34)*WP + (x0 + pp%34))*64 + s*8);
    *(uint4*)(&atile[pp*72 + s*8]) = v;
  }
  for (int e = tid; e < 2*64*9; e += 256) wl[e] = w[e];
  __syncthreads();

  float a0 = bias[0], a1 = bias[1];
  #pragma unroll 1
  for (int tap = 0; tap < 9; ++tap) {
    const int dy = tap / 3, dx = tap - dy*3;
    const __hip_bfloat16* ap = &atile[((ty + dy)*34 + tx + dx)*72];
    #pragma unroll
    for (int s = 0; s < 8; ++s) {
      short8 v8 = *(const short8*)(ap + s*8);
      const __hip_bfloat16* hv = (const __hip_bfloat16*)&v8;
      #pragma unroll
      for (int j = 0; j < 8; ++j) {
        const float f = __bfloat162float(hv[j]);
        a0 = fmaf(f, wl[(s*8 + j)*9 + tap], a0);
        a1 = fmaf(f, wl[(64 + s*8 + j)*9 + tap], a1);
      }
    }
  }
  const float lamv = lam[0];
  const int y = y0 + ty, x = x0 + tx;
  const int idx2 = y*WW + x;
  float xv0 = xcur[b*2*HW + idx2],  xv1 = xcur[b*2*HW + HW + idx2];
  float u0  = under[b*2*HW + idx2], u1  = under[b*2*HW + HW + idx2];
  float r0 = u0 + lamv * (xv0 + a0);
  float r1 = u1 + lamv * (xv1 + a1);
  const int cidx = b*HW + idx2;
  cf vv; vv.x = r0; vv.y = r1;
  r[cidx] = vv; p[cidx] = vv;
  cf zz; zz.x = 0.f; zz.y = 0.f; xc[cidx] = zz;
  float partial = r0*r0 + r1*r1;
  for (int off = 32; off; off >>= 1) partial += __shfl_down(partial, off);
  const int l = tid & 63, wvid = tid >> 6;
  if (l == 0) wsum[wvid] = partial;
  __syncthreads();
  if (tid == 0) atomicAdd(&scL[b], wsum[0]+wsum[1]+wsum[2]+wsum[3]);
}

// ---------------- CG / FFT kernels ----------------
// scL (128 floats/layer): rtr[it*4+b] (it 0..9), pAp[40+it*4+b], ApAp[80+it*4+b].
// rtr recurrence: rtr_new = a^2*ApAp - rtr (Hermitian A).
// t is stored as packed fp16 pairs (4B/complex) to halve the dominant CG
// traffic term (t round trips were 151 MB/iter in fp32).

__global__ void __launch_bounds__(256) update_k(const cf* __restrict__ rold, cf* __restrict__ rnew,
                                                const cf* __restrict__ pold, cf* __restrict__ pnew,
                                                cf* __restrict__ xc, const cf* __restrict__ Ap,
                                                float* __restrict__ scL, int it) {
  const int idx = blockIdx.x * 256 + threadIdx.x;
  const int b = idx / HW;
  const float rtrp  = scL[(it-1)*4 + b];
  const float pApp  = scL[40 + (it-1)*4 + b];
  const float ApApp = scL[80 + (it-1)*4 + b];
  const float alpha = rtrp / pApp;
  const float rtrn  = alpha*alpha*ApApp - rtrp;
  const float beta  = rtrn / rtrp;
  if ((idx - b*HW) == 0) scL[it*4 + b] = rtrn;
  cf rv = rold[idx];
  cf av = Ap[idx];
  rv.x -= alpha*av.x; rv.y -= alpha*av.y;
  cf po = pold[idx];
  cf pv; pv.x = rv.x + beta*po.x; pv.y = rv.y + beta*po.y;
  rnew[idx] = rv;
  pnew[idx] = pv;
  cf xv = xc[idx]; xv.x += alpha*po.x; xv.y += alpha*po.y; xc[idx] = xv;
}

// pass_a: row FFT of csm*p per coil. 4 rows/block (one per wave).
__global__ void __launch_bounds__(256) pass_a_k(const cf* __restrict__ pin,
                                                const cf* __restrict__ csm,
                                                unsigned* __restrict__ t) {
  __shared__ cf rowbuf[4][434];
  const int l = threadIdx.x & 63, wv = threadIdx.x >> 6;
  const int y = blockIdx.x * 4 + wv;
  const int c = blockIdx.y, b = blockIdx.z;
  const cf* prow = pin + b*HW + y*WW;
  const cf* crow = csm + (b*CC + c)*HW + y*WW;
  cf v[6];
  #pragma unroll
  for (int m = 0; m < 6; ++m) v[m] = cmul(crow[l + 64*m], prow[l + 64*m]);
  cf uA[3], uB[3];
  fft384_wave<-1>(l, v, uA, uB);
  const int R3 = 3 * brev7(l);
  cf* rb = rowbuf[wv];                  // wave-private
  #pragma unroll
  for (int k1 = 0; k1 < 3; ++k1) { rb[padi(k1 + R3)] = uA[k1]; rb[padi(k1 + R3 + 3)] = uB[k1]; }
  unsigned* trow = t + (b*CC + c)*HW + y*WW;
  #pragma unroll
  for (int m = 0; m < 6; ++m) trow[l + 64*m] = packh(rb[padi(l + 64*m)]);
}

__global__ void __launch_bounds__(256) pass_b_k(unsigned* __restrict__ t, const float* __restrict__ mask) {
  __shared__ cf tile[431*9];
  const int b = blockIdx.z, c = blockIdx.y, x0 = blockIdx.x * 8;
  unsigned* base = t + (b*CC + c)*HW;
  for (int e = threadIdx.x; e < 3072; e += 256) {
    int y = e >> 3, xx = e & 7;
    tile[padi(y)*9 + xx] = unpackh(base[y*WW + x0 + xx]);
  }
  __syncthreads();
  const int l = threadIdx.x & 63, wv = threadIdx.x >> 6;
  const int R3 = 3 * brev7(l);
  for (int rep = 0; rep < 2; ++rep) {
    const int xx = wv*2 + rep, x = x0 + xx;
    cf v[6];
    #pragma unroll
    for (int m = 0; m < 6; ++m) v[m] = tile[padi(l + 64*m)*9 + xx];
    cf uA[3], uB[3];
    fft384_wave<-1>(l, v, uA, uB);
    const float* mrow = mask + b*HW + x;
    #pragma unroll
    for (int k1 = 0; k1 < 3; ++k1) {
      float mA = mrow[(k1 + R3)*WW], mB = mrow[(k1 + R3 + 3)*WW];
      uA[k1].x *= mA; uA[k1].y *= mA; uB[k1].x *= mB; uB[k1].y *= mB;
    }
    __syncthreads();
    #pragma unroll
    for (int k1 = 0; k1 < 3; ++k1) { tile[padi(k1 + R3)*9 + xx] = uA[k1]; tile[padi(k1 + R3 + 3)*9 + xx] = uB[k1]; }
    __syncthreads();
    #pragma unroll
    for (int m = 0; m < 6; ++m) v[m] = tile[padi(l + 64*m)*9 + xx];
    fft384_wave<1>(l, v, uA, uB);
    const float s = 1.0f / 384.0f;
    #pragma unroll
    for (int k1 = 0; k1 < 3; ++k1) {
      uA[k1].x *= s; uA[k1].y *= s; uB[k1].x *= s; uB[k1].y *= s;
      tile[padi(k1 + R3)*9 + xx] = uA[k1]; tile[padi(k1 + R3 + 3)*9 + xx] = uB[k1];
    }
    __syncthreads();
  }
  for (int e = threadIdx.x; e < 3072; e += 256) {
    int y = e >> 3, xx = e & 7;
    base[y*WW + x0 + xx] = packh(tile[padi(y)*9 + xx]);
  }
}

// pass_c: one y-row per block (HH x BB grid), 8 coils split 2/wave with
// per-coil LDS buffers, then a fully parallel tail: all 4 waves publish acc
// to redbuf, all 256 threads split the 384 columns, block-reduce the dots.
__global__ void __launch_bounds__(256) pass_c_k(const unsigned* __restrict__ t, const cf* __restrict__ csm,
                                                const cf* __restrict__ p, cf* __restrict__ Ap,
                                                const float* __restrict__ lam,
                                                float* __restrict__ scL, int it) {
  __shared__ cf rowbuf[4][2][434];
  __shared__ cf redbuf[4][384];
  __shared__ float wsums[4][2];
  const int tid = threadIdx.x;
  const int l = tid & 63, wv = tid >> 6;
  const int y = blockIdx.x, b = blockIdx.y;
  const int R3 = 3 * brev7(l);
  cf acc[6] = {};
  #pragma unroll
  for (int ci = 0; ci < 2; ++ci) {
    const int c = wv*2 + ci;
    const unsigned* trow = t + (b*CC + c)*HW + y*WW;
    cf v[6];
    #pragma unroll
    for (int m = 0; m < 6; ++m) v[m] = unpackh(trow[l + 64*m]);
    cf uA[3], uB[3];
    fft384_wave<1>(l, v, uA, uB);
    cf* rb = rowbuf[wv][ci];            // wave-private, per-coil buffer
    #pragma unroll
    for (int k1 = 0; k1 < 3; ++k1) { rb[padi(k1 + R3)] = uA[k1]; rb[padi(k1 + R3 + 3)] = uB[k1]; }
    const cf* crow = csm + (b*CC + c)*HW + y*WW;
    #pragma unroll
    for (int m = 0; m < 6; ++m) {
      cf cs = crow[l + 64*m];
      cf wz = rb[padi(l + 64*m)];
      acc[m].x += cs.x*wz.x + cs.y*wz.y;
      acc[m].y += cs.x*wz.y - cs.y*wz.x;
    }
  }
  #pragma unroll
  for (int m = 0; m < 6; ++m) redbuf[wv][m*64 + l] = acc[m];
  __syncthreads();

  const float lamv = lam[0];
  const float sc384 = 1.0f / 384.0f;
  const cf* prow = p + b*HW + y*WW;
  cf* aprow = Ap + b*HW + y*WW;
  float partial = 0.f, partial2 = 0.f;
  #pragma unroll
  for (int rep = 0; rep < 2; ++rep) {
    const int pos = rep*256 + tid;
    if (pos < 384) {
      cf s0 = redbuf[0][pos], s1 = redbuf[1][pos], s2 = redbuf[2][pos], s3 = redbuf[3][pos];
      cf s; s.x = (s0.x + s1.x) + (s2.x + s3.x); s.y = (s0.y + s1.y) + (s2.y + s3.y);
      cf pv = prow[pos];
      cf ap; ap.x = s.x*sc384 + lamv*pv.x; ap.y = s.y*sc384 + lamv*pv.y;
      aprow[pos] = ap;
      partial  += pv.x*ap.x + pv.y*ap.y;
      partial2 += ap.x*ap.x + ap.y*ap.y;
    }
  }
  #pragma unroll
  for (int off = 32; off; off >>= 1) {
    partial  += __shfl_down(partial, off);
    partial2 += __shfl_down(partial2, off);
  }
  if (l == 0) { wsums[wv][0] = partial; wsums[wv][1] = partial2; }
  __syncthreads();
  if (tid == 0) {
    atomicAdd(&scL[40 + it*4 + b], (wsums[0][0]+wsums[1][0])+(wsums[2][0]+wsums[3][0]));
    atomicAdd(&scL[80 + it*4 + b], (wsums[0][1]+wsums[1][1])+(wsums[2][1]+wsums[3][1]));
  }
}

// final x = xc + alpha9 * p9, planar output
__global__ void __launch_bounds__(256) final_x_k(const cf* __restrict__ xc, const cf* __restrict__ p9,
                                                 const float* __restrict__ scL, float* __restrict__ out) {
  const int idx = blockIdx.x * 256 + threadIdx.x;
  const int b = idx / HW;
  const int rem = idx - b*HW;
  const float alpha = scL[(CGITERS-1)*4 + b] / scL[40 + (CGITERS-1)*4 + b];
  cf xv = xc[idx], pv = p9[idx];
  xv.x += alpha*pv.x; xv.y += alpha*pv.y;
  out[b*2*HW + rem] = xv.x;
  out[b*2*HW + HW + rem] = xv.y;
}

__global__ void zero_sc_k(float* sc) {
  for (int i = threadIdx.x; i < NLAYERS*128; i += 256) sc[i] = 0.f;
}

extern "C" void kernel_launch(void* const* d_in, const int* in_sizes, int n_in,
                              void* d_out, int out_size, void* d_ws, size_t ws_size,
                              hipStream_t stream) {
  (void)in_sizes; (void)n_in; (void)out_size; (void)ws_size;
  const float* under  = (const float*)d_in[0];
  const cf*    csm    = (const cf*)d_in[1];
  const float* mask   = (const float*)d_in[2];
  const float* lam    = (const float*)d_in[3];
  const float* w_in   = (const float*)d_in[4];
  const float* b_in   = (const float*)d_in[5];
  const float* ws_mid = (const float*)d_in[6];
  const float* bs_mid = (const float*)d_in[7];
  const float* w_out  = (const float*)d_in[8];
  const float* b_out  = (const float*)d_in[9];
  float* xcur = (float*)d_out;

  char* bws = (char*)d_ws;
  size_t off = 0;
  auto carve = [&](size_t bytes) { char* pp = bws + off; off += (bytes + 255) & ~(size_t)255; return (void*)pp; };
  __hip_bfloat16* actA = (__hip_bfloat16*)carve((size_t)BB*PP*64*2);
  __hip_bfloat16* actB = (__hip_bfloat16*)carve((size_t)BB*PP*64*2);
  unsigned* t = (unsigned*)carve((size_t)BB*CC*HW*4);   // packed fp16 pairs
  cf* rbuf0 = (cf*)carve((size_t)BB*HW*8);
  cf* rbuf1 = (cf*)carve((size_t)BB*HW*8);
  cf* pbuf0 = (cf*)carve((size_t)BB*HW*8);
  cf* pbuf1 = (cf*)carve((size_t)BB*HW*8);
  cf* xc    = (cf*)carve((size_t)BB*HW*8);
  cf* Ap    = (cf*)carve((size_t)BB*HW*8);
  float* sc = (float*)carve(4096);
  __hip_bfloat16* wrep = (__hip_bfloat16*)carve((size_t)7*9*64*64*2);

  hipMemcpyAsync(xcur, under, (size_t)BB*2*HW*sizeof(float), hipMemcpyDeviceToDevice, stream);

  zero_sc_k<<<1, 256, 0, stream>>>(sc);
  repack_mid_k<<<(7*9*64*64 + 255)/256, 256, 0, stream>>>(ws_mid, wrep);
  zero_guard_k<<<(2*BB*1540*8 + 255)/256, 256, 0, stream>>>(actA, actB);

  dim3 cgrid(WW/32, HH/8, BB);       // conv_in / conv_mid / conv_out (32x8 tiles)
  dim3 agrid(HH/4, CC, BB);
  dim3 bgrid(WW/8, CC, BB);
  dim3 c2grid(HH, BB);               // pass_c: one row per block
  const int egrid = BB*HW/256;

  __hip_bfloat16* bufs[2] = { actA, actB };
  cf* rb[2] = { rbuf0, rbuf1 };
  cf* pb[2] = { pbuf0, pbuf1 };

  for (int layer = 0; layer < NLAYERS; ++layer) {
    float* scL = sc + layer*128;
    conv_in_k<<<cgrid, 256, 0, stream>>>(xcur, w_in, b_in, bufs[0]);
    for (int i = 0; i < 7; ++i) {
      conv_mid_mfma_k<<<cgrid, 256, 0, stream>>>(bufs[i & 1], wrep + (size_t)i*9*4096,
                                                 bs_mid + i*64, bufs[(i + 1) & 1], (i % 2 == 0) ? 1 : 0);
    }
    conv_out_k<<<cgrid, 256, 0, stream>>>(bufs[1], w_out, b_out, xcur, under, lam,
                                          rbuf0, pbuf0, xc, scL);
    for (int it = 0; it < CGITERS; ++it) {
      cf* rold = rb[(it + 1) & 1];
      cf* rnew = rb[it & 1];
      cf* pold = pb[(it + 1) & 1];
      cf* pnew = pb[it & 1];
      if (it == 0) { rold = rbuf0; pold = pbuf0; rnew = rbuf0; pnew = pbuf0; }
      if (it > 0)
        update_k<<<egrid, 256, 0, stream>>>(rold, rnew, pold, pnew, xc, Ap, scL, it);
      pass_a_k<<<agrid, 256, 0, stream>>>(pnew, csm, t);
      pass_b_k<<<bgrid, 256, 0, stream>>>(t, mask);
      pass_c_k<<<c2grid, 256, 0, stream>>>(t, csm, pnew, Ap, lam, scL, it);
    }
    final_x_k<<<egrid, 256, 0, stream>>>(xc, pb[(CGITERS - 1) & 1], scL, xcur);
  }
}

// Round 7
// 8972.551 us; speedup vs baseline: 1.2103x; 1.0006x over previous
//
#include <hip/hip_runtime.h>
#include <hip/hip_bf16.h>
#include <hip/hip_fp16.h>
#include <math.h>

#define HH 384
#define WW 384
#define HW (HH*WW)
#define WP 386              // padded row stride (1-px guard ring)
#define PP (386*386)        // padded image pixels
#define BB 4
#define CC 8
#define NLAYERS 5
#define CGITERS 10
#define PI_F 3.14159265358979323846f

typedef __attribute__((ext_vector_type(8))) short short8;
typedef __attribute__((ext_vector_type(4))) float floatx4;

struct cf { float x, y; };
__device__ __forceinline__ cf cadd(cf a, cf b){ cf r; r.x=a.x+b.x; r.y=a.y+b.y; return r; }
__device__ __forceinline__ cf csub(cf a, cf b){ cf r; r.x=a.x-b.x; r.y=a.y-b.y; return r; }
__device__ __forceinline__ cf cmul(cf a, cf b){ cf r; r.x=a.x*b.x - a.y*b.y; r.y=a.x*b.y + a.y*b.x; return r; }
__device__ __forceinline__ cf csqr(cf a){ cf r; r.x = a.x*a.x - a.y*a.y; r.y = 2.f*a.x*a.y; return r; }
__device__ __forceinline__ cf shflxor(cf v, int m){ cf r; r.x = __shfl_xor(v.x, m); r.y = __shfl_xor(v.y, m); return r; }
__device__ __forceinline__ int brev7(int l){ return (int)(__brev((unsigned)l) >> 25); }
__device__ __forceinline__ int padi(int i){ return i + (i >> 3); }

// packed fp16 complex (4B). Arithmetic stays fp32; fp16 rel-err 0.05%;
// clamp guards the 65504 range edge. Used for t (r6-verified: -446us,
// absmax improved) and now csm (read 2x/iter, 75.5 MB/iter in fp32).
__device__ __forceinline__ unsigned packh(cf v) {
  __half hx = __float2half(fminf(fmaxf(v.x, -60000.f), 60000.f));
  __half hy = __float2half(fminf(fmaxf(v.y, -60000.f), 60000.f));
  unsigned short ux = *(unsigned short*)&hx, uy = *(unsigned short*)&hy;
  return (unsigned)ux | ((unsigned)uy << 16);
}
__device__ __forceinline__ cf unpackh(unsigned u) {
  unsigned short ux = (unsigned short)(u & 0xffffu), uy = (unsigned short)(u >> 16);
  __half hx = *(__half*)&ux, hy = *(__half*)&uy;
  cf r; r.x = __half2float(hx); r.y = __half2float(hy); return r;
}

__device__ __forceinline__ void radix3(cf a0, cf a1, cf a2, float s3, cf y[3]) {
  float tx = a1.x + a2.x, ty_ = a1.y + a2.y;
  float ux = a1.x - a2.x, uy = a1.y - a2.y;
  y[0].x = a0.x + tx;              y[0].y = a0.y + ty_;
  y[1].x = a0.x - 0.5f*tx - s3*uy; y[1].y = a0.y - 0.5f*ty_ + s3*ux;
  y[2].x = a0.x - 0.5f*tx + s3*uy; y[2].y = a0.y - 0.5f*ty_ - s3*ux;
}

// 384-point DFT across one 64-lane wave. SIGN=-1 fwd, +1 inverse (no 1/N scale).
template<int SIGN>
__device__ __forceinline__ void fft384_wave(int l, const cf v[6], cf uA[3], cf uB[3]) {
  const float s3 = SIGN * 0.8660254037844386f;
  radix3(v[0], v[2], v[4], s3, uA);
  radix3(v[1], v[3], v[5], s3, uB);
  float sA, cA;
  __sincosf(SIGN * (2.0f * PI_F / 384.0f) * (float)l, &sA, &cA);
  cf wA1; wA1.x = cA; wA1.y = sA;
  cf wA2 = csqr(wA1);
  cf w6; w6.x = 0.5f; w6.y = s3;            // exp(SIGN*i*pi/3)
  cf wB1 = cmul(wA1, w6);
  cf wB2 = csqr(wB1);
  uA[1] = cmul(uA[1], wA1); uA[2] = cmul(uA[2], wA2);
  uB[1] = cmul(uB[1], wB1); uB[2] = cmul(uB[2], wB2);
  cf u = cmul(wA2, wA1);                    // exp(SIGN*i*pi*l/64): stage h=64 twiddle
  #pragma unroll
  for (int k1 = 0; k1 < 3; ++k1) {
    cf a = uA[k1], b = uB[k1];
    uA[k1] = cadd(a, b);
    uB[k1] = cmul(csub(a, b), u);
  }
  #pragma unroll
  for (int h = 32; h >= 1; h >>= 1) {
    u = csqr(u);                             // exp(SIGN*i*pi*l/h)
    const bool up = (l & h) != 0;
    #pragma unroll
    for (int k1 = 0; k1 < 3; ++k1) {
      cf pa = shflxor(uA[k1], h);
      cf pb = shflxor(uB[k1], h);
      cf na = up ? cmul(csub(uA[k1], pa), u) : cadd(uA[k1], pa);
      cf nb = up ? cmul(csub(uB[k1], pb), u) : cadd(uB[k1], pb);
      uA[k1] = na; uB[k1] = nb;
    }
  }
}

// ---------------- conv kernels ----------------
// Activations in PADDED NHWC bf16: act[b][y+1][x+1][c], row stride WP=386,
// c=64 contiguous. 1-px guard ring zeroed once per launch; conv stores only
// write interior -> guards stay zero -> halo reads need NO bounds checks.

__global__ void repack_mid_k(const float* __restrict__ ws_mid, __hip_bfloat16* __restrict__ wrep) {
  const int idx = blockIdx.x * 256 + threadIdx.x;
  if (idx >= 7*9*64*64) return;
  const int ci = idx & 63, co = (idx >> 6) & 63, tap = (idx >> 12) % 9, i = idx / (9*4096);
  wrep[idx] = __float2bfloat16(ws_mid[(((size_t)i*64 + co)*64 + ci)*9 + tap]);
}

// repack csm (fp32 cf) -> packed fp16 pairs, once per launch
__global__ void repack_csm_k(const cf* __restrict__ csm, unsigned* __restrict__ csmh) {
  const int idx = blockIdx.x * 256 + threadIdx.x;
  if (idx >= BB*CC*HW) return;
  csmh[idx] = packh(csm[idx]);
}

// zero the guard ring of both activation buffers (1540 px per image per buf)
__global__ void zero_guard_k(__hip_bfloat16* __restrict__ a, __hip_bfloat16* __restrict__ b2) {
  const int idx = blockIdx.x * 256 + threadIdx.x;
  if (idx >= 2*BB*1540*8) return;
  const int s = idx & 7; int rest = idx >> 3;
  const int px = rest % 1540; rest /= 1540;
  const int bb = rest & 3; const int buf = rest >> 2;
  int row, col;
  if (px < WP)        { row = 0;    col = px; }
  else if (px < 2*WP) { row = HH+1; col = px - WP; }
  else { const int k = px - 2*WP; row = 1 + (k >> 1); col = (k & 1) ? (WW+1) : 0; }
  __hip_bfloat16* base = buf ? b2 : a;
  *(uint4*)(base + ((size_t)bb*PP + (size_t)row*WP + col)*64 + s*8) = make_uint4(0u,0u,0u,0u);
}

__global__ void __launch_bounds__(256) conv_in_k(const float* __restrict__ xin,
                                                 const float* __restrict__ w,
                                                 const float* __restrict__ bias,
                                                 __hip_bfloat16* __restrict__ out) {
  __shared__ float tile[2][340];
  const int tx = threadIdx.x & 31, ty = threadIdx.x >> 5;
  const int x0 = blockIdx.x * 32, y0 = blockIdx.y * 8, b = blockIdx.z;
  for (int e = threadIdx.x; e < 680; e += 256) {
    int ci = e / 340, rr = e % 340;
    int iy = y0 - 1 + rr / 34, ix = x0 - 1 + rr % 34;
    float v = 0.f;
    if (iy >= 0 && iy < HH && ix >= 0 && ix < WW)
      v = xin[(b*2 + ci)*HW + iy*WW + ix];
    tile[ci][rr] = v;
  }
  __syncthreads();
  float acc[64];
  #pragma unroll
  for (int co = 0; co < 64; ++co) acc[co] = bias[co];
  #pragma unroll
  for (int ci = 0; ci < 2; ++ci) {
    float v0 = tile[ci][ty*34+tx],     v1 = tile[ci][ty*34+tx+1],     v2 = tile[ci][ty*34+tx+2];
    float v3 = tile[ci][(ty+1)*34+tx], v4 = tile[ci][(ty+1)*34+tx+1], v5 = tile[ci][(ty+1)*34+tx+2];
    float v6 = tile[ci][(ty+2)*34+tx], v7 = tile[ci][(ty+2)*34+tx+1], v8 = tile[ci][(ty+2)*34+tx+2];
    #pragma unroll
    for (int co = 0; co < 64; ++co) {
      const float* wp = w + co*18 + ci*9;
      float a = acc[co];
      a = fmaf(v0, wp[0], a); a = fmaf(v1, wp[1], a); a = fmaf(v2, wp[2], a);
      a = fmaf(v3, wp[3], a); a = fmaf(v4, wp[4], a); a = fmaf(v5, wp[5], a);
      a = fmaf(v6, wp[6], a); a = fmaf(v7, wp[7], a); a = fmaf(v8, wp[8], a);
      acc[co] = a;
    }
  }
  const size_t obase = ((size_t)b*PP + (size_t)(y0 + ty + 1)*WP + (x0 + tx + 1))*64;
  #pragma unroll
  for (int s = 0; s < 8; ++s) {
    uint4 u;
    __hip_bfloat16* hp = (__hip_bfloat16*)&u;
    #pragma unroll
    for (int j = 0; j < 8; ++j) hp[j] = __float2bfloat16(acc[s*8 + j]);
    *(uint4*)(out + obase + s*8) = u;
  }
}

// MFMA implicit-GEMM mid conv (r2 structure, best measured 107.6us, padded):
// - 256 thr / 4 waves, 32x8 tile, 2 blocks/CU co-resident (register-limited;
//   persistent/1-block variant lost inter-block overlap: 128us).
// - branch-free global_load_lds DMA staging for ALL blocks (padded halo).
// - rolled tap loop + one-tap-ahead weight dbuf (full unroll spills).
// - both-sides XOR channel-group swizzle (bank conflicts 2.95M -> 0.3M).
__global__ void __launch_bounds__(256) conv_mid_mfma_k(
    const __hip_bfloat16* __restrict__ in,    // padded NHWC
    const __hip_bfloat16* __restrict__ wrep,  // [9][64][64] bf16
    const float* __restrict__ bias,
    __hip_bfloat16* __restrict__ out, int relu) {
  __shared__ __align__(16) __hip_bfloat16 atile[2752*8];  // 44032 B (32 pad slots)
  const int tid = threadIdx.x;
  const int l = tid & 63, wv = tid >> 6;
  const int x0 = blockIdx.x * 32, y0 = blockIdx.y * 8, b = blockIdx.z;

  const int kseg = l >> 4;
  const int lr = l & 15;

  // weight prefetch for tap 0 (L2-resident, issued before staging drain)
  const __hip_bfloat16* wlane = wrep + lr*64 + kseg*8;
  short8 bf[4][2];
  #pragma unroll
  for (int nt = 0; nt < 4; ++nt) {
    bf[nt][0] = *(const short8*)(wlane + nt*1024);
    bf[nt][1] = *(const short8*)(wlane + nt*1024 + 32);
  }

  // ---- stage A-tile: 340 px * 8 slots = 2720 16B slots, DMA path.
  // slot (p, s) <- channel-group s^(p&7) of halo pixel p (XOR swizzle).
  const __hip_bfloat16* inb = in + (size_t)b*PP*64;
  #pragma unroll
  for (int i = 0; i < 10; ++i) {
    const int j = i*256 + tid;
    const int p = j >> 3, s = j & 7;
    const int g = s ^ (p & 7);
    const __hip_bfloat16* src = inb + ((size_t)(y0 + p/34)*WP + (x0 + p%34))*64 + g*8;
    __builtin_amdgcn_global_load_lds(
        (const __attribute__((address_space(1))) void*)src,
        (__attribute__((address_space(3))) void*)(atile + (i*256 + wv*64)*8),
        16, 0, 0);
  }
  if (tid < 160) {                             // tail slots 2560..2719
    const int j = 2560 + tid;
    const int p = j >> 3, s = j & 7;
    const int g = s ^ (p & 7);
    uint4 v = *(const uint4*)(inb + ((size_t)(y0 + p/34)*WP + (x0 + p%34))*64 + g*8);
    *(uint4*)(atile + j*8) = v;
  }

  floatx4 acc[4][4];
  #pragma unroll
  for (int mt = 0; mt < 4; ++mt)
    #pragma unroll
    for (int nt = 0; nt < 4; ++nt)
      acc[mt][nt] = (floatx4){0.f, 0.f, 0.f, 0.f};

  __syncthreads();

  #pragma unroll 1
  for (int tap = 0; tap < 9; ++tap) {
    short8 bfn[4][2];
    if (tap < 8) {
      const __hip_bfloat16* wn = wlane + (tap + 1)*4096;
      #pragma unroll
      for (int nt = 0; nt < 4; ++nt) {
        bfn[nt][0] = *(const short8*)(wn + nt*1024);
        bfn[nt][1] = *(const short8*)(wn + nt*1024 + 32);
      }
    }
    const int dy = tap / 3, dx = tap - dy*3;
    short8 af[4][2];
    #pragma unroll
    for (int mt = 0; mt < 4; ++mt) {
      const int ry = 2*wv + (mt >> 1) + dy;
      const int px = (mt & 1)*16 + lr + dx;
      const int p  = ry*34 + px;
      const int eo = p*64 + ((kseg ^ (p & 7)) << 3);   // swizzled elem offset
      af[mt][0] = *(const short8*)(atile + eo);
      af[mt][1] = *(const short8*)(atile + (eo ^ 32)); // (kseg+4)^(p&7) slot
    }
    #pragma unroll
    for (int mt = 0; mt < 4; ++mt)
      #pragma unroll
      for (int nt = 0; nt < 4; ++nt) {
        acc[mt][nt] = __builtin_amdgcn_mfma_f32_16x16x32_bf16(af[mt][0], bf[nt][0], acc[mt][nt], 0, 0, 0);
        acc[mt][nt] = __builtin_amdgcn_mfma_f32_16x16x32_bf16(af[mt][1], bf[nt][1], acc[mt][nt], 0, 0, 0);
      }
    if (tap < 8) {
      #pragma unroll
      for (int nt = 0; nt < 4; ++nt) { bf[nt][0] = bfn[nt][0]; bf[nt][1] = bfn[nt][1]; }
    }
  }

  // LDS-transpose epilogue -> coalesced 16B stores (reuses atile as [256][72])
  __syncthreads();
  __hip_bfloat16* otile = atile;
  #pragma unroll
  for (int mt = 0; mt < 4; ++mt) {
    const int row = 2*wv + (mt >> 1);
    #pragma unroll
    for (int nt = 0; nt < 4; ++nt) {
      const int ch = nt*16 + lr;
      const float bv = bias[ch];
      #pragma unroll
      for (int rr = 0; rr < 4; ++rr) {
        const int px = (mt & 1)*16 + kseg*4 + rr;
        float v = acc[mt][nt][rr] + bv;
        if (relu) v = fmaxf(v, 0.f);
        otile[(row*32 + px)*72 + ch] = __float2bfloat16(v);
      }
    }
  }
  __syncthreads();
  #pragma unroll
  for (int iter = 0; iter < 8; ++iter) {
    const int p = iter*32 + (tid >> 3), s = tid & 7;
    const int row = p >> 5, px = p & 31;
    uint4 v = *(const uint4*)(&otile[p*72 + s*8]);
    *(uint4*)(out + ((size_t)b*PP + (size_t)(y0 + row + 1)*WP + (x0 + px + 1))*64 + s*8) = v;
  }
}

// conv_out (co=2) + CG init, LDS-staged (padded input -> no bounds checks)
__global__ void __launch_bounds__(256) conv_out_k(const __hip_bfloat16* __restrict__ in,
                                                  const float* __restrict__ w,
                                                  const float* __restrict__ bias,
                                                  const float* __restrict__ xcur,
                                                  const float* __restrict__ under,
                                                  const float* __restrict__ lam,
                                                  cf* __restrict__ r, cf* __restrict__ p,
                                                  cf* __restrict__ xc, float* __restrict__ scL) {
  __shared__ __hip_bfloat16 atile[340*72];
  __shared__ float wl[2*64*9];
  __shared__ float wsum[4];
  const int tid = threadIdx.x;
  const int tx = tid & 31, ty = tid >> 5;
  const int x0 = blockIdx.x * 32, y0 = blockIdx.y * 8, b = blockIdx.z;

  for (int e = tid; e < 340*8; e += 256) {
    int pp = e >> 3, s = e & 7;
    uint4 v = *(const uint4*)(in + ((size_t)b*PP + (size_t)(y0 + pp/34)*WP + (x0 + pp%34))*64 + s*8);
    *(uint4*)(&atile[pp*72 + s*8]) = v;
  }
  for (int e = tid; e < 2*64*9; e += 256) wl[e] = w[e];
  __syncthreads();

  float a0 = bias[0], a1 = bias[1];
  #pragma unroll 1
  for (int tap = 0; tap < 9; ++tap) {
    const int dy = tap / 3, dx = tap - dy*3;
    const __hip_bfloat16* ap = &atile[((ty + dy)*34 + tx + dx)*72];
    #pragma unroll
    for (int s = 0; s < 8; ++s) {
      short8 v8 = *(const short8*)(ap + s*8);
      const __hip_bfloat16* hv = (const __hip_bfloat16*)&v8;
      #pragma unroll
      for (int j = 0; j < 8; ++j) {
        const float f = __bfloat162float(hv[j]);
        a0 = fmaf(f, wl[(s*8 + j)*9 + tap], a0);
        a1 = fmaf(f, wl[(64 + s*8 + j)*9 + tap], a1);
      }
    }
  }
  const float lamv = lam[0];
  const int y = y0 + ty, x = x0 + tx;
  const int idx2 = y*WW + x;
  float xv0 = xcur[b*2*HW + idx2],  xv1 = xcur[b*2*HW + HW + idx2];
  float u0  = under[b*2*HW + idx2], u1  = under[b*2*HW + HW + idx2];
  float r0 = u0 + lamv * (xv0 + a0);
  float r1 = u1 + lamv * (xv1 + a1);
  const int cidx = b*HW + idx2;
  cf vv; vv.x = r0; vv.y = r1;
  r[cidx] = vv; p[cidx] = vv;
  cf zz; zz.x = 0.f; zz.y = 0.f; xc[cidx] = zz;
  float partial = r0*r0 + r1*r1;
  for (int off = 32; off; off >>= 1) partial += __shfl_down(partial, off);
  const int l = tid & 63, wvid = tid >> 6;
  if (l == 0) wsum[wvid] = partial;
  __syncthreads();
  if (tid == 0) atomicAdd(&scL[b], wsum[0]+wsum[1]+wsum[2]+wsum[3]);
}

// ---------------- CG / FFT kernels ----------------
// scL (128 floats/layer): rtr[it*4+b] (it 0..9), pAp[40+it*4+b], ApAp[80+it*4+b].
// rtr recurrence: rtr_new = a^2*ApAp - rtr (Hermitian A).
// t AND csm stored as packed fp16 pairs (4B/complex): t halving verified
// r6 (-446us, absmax improved); csm was the next-largest term (75.5 MB/iter).

// update: 2 complexes per thread (float4), halves instruction count.
__global__ void __launch_bounds__(256) update_k(const float4* __restrict__ rold, float4* __restrict__ rnew,
                                                const float4* __restrict__ pold, float4* __restrict__ pnew,
                                                float4* __restrict__ xc, const float4* __restrict__ Ap,
                                                float* __restrict__ scL, int it) {
  const int idx = blockIdx.x * 256 + threadIdx.x;   // over BB*HW/2
  const int b = idx / (HW/2);
  const float rtrp  = scL[(it-1)*4 + b];
  const float pApp  = scL[40 + (it-1)*4 + b];
  const float ApApp = scL[80 + (it-1)*4 + b];
  const float alpha = rtrp / pApp;
  const float rtrn  = alpha*alpha*ApApp - rtrp;
  const float beta  = rtrn / rtrp;
  if ((idx - b*(HW/2)) == 0) scL[it*4 + b] = rtrn;
  float4 rv = rold[idx];
  float4 av = Ap[idx];
  rv.x -= alpha*av.x; rv.y -= alpha*av.y; rv.z -= alpha*av.z; rv.w -= alpha*av.w;
  float4 po = pold[idx];
  float4 pv;
  pv.x = rv.x + beta*po.x; pv.y = rv.y + beta*po.y;
  pv.z = rv.z + beta*po.z; pv.w = rv.w + beta*po.w;
  rnew[idx] = rv;
  pnew[idx] = pv;
  float4 xv = xc[idx];
  xv.x += alpha*po.x; xv.y += alpha*po.y; xv.z += alpha*po.z; xv.w += alpha*po.w;
  xc[idx] = xv;
}

// pass_a: row FFT of csm*p per coil. 4 rows/block (one per wave).
__global__ void __launch_bounds__(256) pass_a_k(const cf* __restrict__ pin,
                                                const unsigned* __restrict__ csmh,
                                                unsigned* __restrict__ t) {
  __shared__ cf rowbuf[4][434];
  const int l = threadIdx.x & 63, wv = threadIdx.x >> 6;
  const int y = blockIdx.x * 4 + wv;
  const int c = blockIdx.y, b = blockIdx.z;
  const cf* prow = pin + b*HW + y*WW;
  const unsigned* crow = csmh + (b*CC + c)*HW + y*WW;
  cf v[6];
  #pragma unroll
  for (int m = 0; m < 6; ++m) v[m] = cmul(unpackh(crow[l + 64*m]), prow[l + 64*m]);
  cf uA[3], uB[3];
  fft384_wave<-1>(l, v, uA, uB);
  const int R3 = 3 * brev7(l);
  cf* rb = rowbuf[wv];                  // wave-private
  #pragma unroll
  for (int k1 = 0; k1 < 3; ++k1) { rb[padi(k1 + R3)] = uA[k1]; rb[padi(k1 + R3 + 3)] = uB[k1]; }
  unsigned* trow = t + (b*CC + c)*HW + y*WW;
  #pragma unroll
  for (int m = 0; m < 6; ++m) trow[l + 64*m] = packh(rb[padi(l + 64*m)]);
}

__global__ void __launch_bounds__(256) pass_b_k(unsigned* __restrict__ t, const float* __restrict__ mask) {
  __shared__ cf tile[431*9];
  const int b = blockIdx.z, c = blockIdx.y, x0 = blockIdx.x * 8;
  unsigned* base = t + (b*CC + c)*HW;
  for (int e = threadIdx.x; e < 3072; e += 256) {
    int y = e >> 3, xx = e & 7;
    tile[padi(y)*9 + xx] = unpackh(base[y*WW + x0 + xx]);
  }
  __syncthreads();
  const int l = threadIdx.x & 63, wv = threadIdx.x >> 6;
  const int R3 = 3 * brev7(l);
  for (int rep = 0; rep < 2; ++rep) {
    const int xx = wv*2 + rep, x = x0 + xx;
    cf v[6];
    #pragma unroll
    for (int m = 0; m < 6; ++m) v[m] = tile[padi(l + 64*m)*9 + xx];
    cf uA[3], uB[3];
    fft384_wave<-1>(l, v, uA, uB);
    const float* mrow = mask + b*HW + x;
    #pragma unroll
    for (int k1 = 0; k1 < 3; ++k1) {
      float mA = mrow[(k1 + R3)*WW], mB = mrow[(k1 + R3 + 3)*WW];
      uA[k1].x *= mA; uA[k1].y *= mA; uB[k1].x *= mB; uB[k1].y *= mB;
    }
    __syncthreads();
    #pragma unroll
    for (int k1 = 0; k1 < 3; ++k1) { tile[padi(k1 + R3)*9 + xx] = uA[k1]; tile[padi(k1 + R3 + 3)*9 + xx] = uB[k1]; }
    __syncthreads();
    #pragma unroll
    for (int m = 0; m < 6; ++m) v[m] = tile[padi(l + 64*m)*9 + xx];
    fft384_wave<1>(l, v, uA, uB);
    const float s = 1.0f / 384.0f;
    #pragma unroll
    for (int k1 = 0; k1 < 3; ++k1) {
      uA[k1].x *= s; uA[k1].y *= s; uB[k1].x *= s; uB[k1].y *= s;
      tile[padi(k1 + R3)*9 + xx] = uA[k1]; tile[padi(k1 + R3 + 3)*9 + xx] = uB[k1];
    }
    __syncthreads();
  }
  for (int e = threadIdx.x; e < 3072; e += 256) {
    int y = e >> 3, xx = e & 7;
    base[y*WW + x0 + xx] = packh(tile[padi(y)*9 + xx]);
  }
}

// pass_c: one y-row per block (HH x BB grid), 8 coils split 2/wave with
// per-coil LDS buffers, then a fully parallel tail: all 4 waves publish acc
// to redbuf, all 256 threads split the 384 columns, block-reduce the dots.
__global__ void __launch_bounds__(256) pass_c_k(const unsigned* __restrict__ t,
                                                const unsigned* __restrict__ csmh,
                                                const cf* __restrict__ p, cf* __restrict__ Ap,
                                                const float* __restrict__ lam,
                                                float* __restrict__ scL, int it) {
  __shared__ cf rowbuf[4][2][434];
  __shared__ cf redbuf[4][384];
  __shared__ float wsums[4][2];
  const int tid = threadIdx.x;
  const int l = tid & 63, wv = tid >> 6;
  const int y = blockIdx.x, b = blockIdx.y;
  const int R3 = 3 * brev7(l);
  cf acc[6] = {};
  #pragma unroll
  for (int ci = 0; ci < 2; ++ci) {
    const int c = wv*2 + ci;
    const unsigned* trow = t + (b*CC + c)*HW + y*WW;
    cf v[6];
    #pragma unroll
    for (int m = 0; m < 6; ++m) v[m] = unpackh(trow[l + 64*m]);
    cf uA[3], uB[3];
    fft384_wave<1>(l, v, uA, uB);
    cf* rb = rowbuf[wv][ci];            // wave-private, per-coil buffer
    #pragma unroll
    for (int k1 = 0; k1 < 3; ++k1) { rb[padi(k1 + R3)] = uA[k1]; rb[padi(k1 + R3 + 3)] = uB[k1]; }
    const unsigned* crow = csmh + (b*CC + c)*HW + y*WW;
    #pragma unroll
    for (int m = 0; m < 6; ++m) {
      cf cs = unpackh(crow[l + 64*m]);
      cf wz = rb[padi(l + 64*m)];
      acc[m].x += cs.x*wz.x + cs.y*wz.y;
      acc[m].y += cs.x*wz.y - cs.y*wz.x;
    }
  }
  #pragma unroll
  for (int m = 0; m < 6; ++m) redbuf[wv][m*64 + l] = acc[m];
  __syncthreads();

  const float lamv = lam[0];
  const float sc384 = 1.0f / 384.0f;
  const cf* prow = p + b*HW + y*WW;
  cf* aprow = Ap + b*HW + y*WW;
  float partial = 0.f, partial2 = 0.f;
  #pragma unroll
  for (int rep = 0; rep < 2; ++rep) {
    const int pos = rep*256 + tid;
    if (pos < 384) {
      cf s0 = redbuf[0][pos], s1 = redbuf[1][pos], s2 = redbuf[2][pos], s3 = redbuf[3][pos];
      cf s; s.x = (s0.x + s1.x) + (s2.x + s3.x); s.y = (s0.y + s1.y) + (s2.y + s3.y);
      cf pv = prow[pos];
      cf ap; ap.x = s.x*sc384 + lamv*pv.x; ap.y = s.y*sc384 + lamv*pv.y;
      aprow[pos] = ap;
      partial  += pv.x*ap.x + pv.y*ap.y;
      partial2 += ap.x*ap.x + ap.y*ap.y;
    }
  }
  #pragma unroll
  for (int off = 32; off; off >>= 1) {
    partial  += __shfl_down(partial, off);
    partial2 += __shfl_down(partial2, off);
  }
  if (l == 0) { wsums[wv][0] = partial; wsums[wv][1] = partial2; }
  __syncthreads();
  if (tid == 0) {
    atomicAdd(&scL[40 + it*4 + b], (wsums[0][0]+wsums[1][0])+(wsums[2][0]+wsums[3][0]));
    atomicAdd(&scL[80 + it*4 + b], (wsums[0][1]+wsums[1][1])+(wsums[2][1]+wsums[3][1]));
  }
}

// final x = xc + alpha9 * p9, planar output
__global__ void __launch_bounds__(256) final_x_k(const cf* __restrict__ xc, const cf* __restrict__ p9,
                                                 const float* __restrict__ scL, float* __restrict__ out) {
  const int idx = blockIdx.x * 256 + threadIdx.x;
  const int b = idx / HW;
  const int rem = idx - b*HW;
  const float alpha = scL[(CGITERS-1)*4 + b] / scL[40 + (CGITERS-1)*4 + b];
  cf xv = xc[idx], pv = p9[idx];
  xv.x += alpha*pv.x; xv.y += alpha*pv.y;
  out[b*2*HW + rem] = xv.x;
  out[b*2*HW + HW + rem] = xv.y;
}

__global__ void zero_sc_k(float* sc) {
  for (int i = threadIdx.x; i < NLAYERS*128; i += 256) sc[i] = 0.f;
}

extern "C" void kernel_launch(void* const* d_in, const int* in_sizes, int n_in,
                              void* d_out, int out_size, void* d_ws, size_t ws_size,
                              hipStream_t stream) {
  (void)in_sizes; (void)n_in; (void)out_size; (void)ws_size;
  const float* under  = (const float*)d_in[0];
  const cf*    csm    = (const cf*)d_in[1];
  const float* mask   = (const float*)d_in[2];
  const float* lam    = (const float*)d_in[3];
  const float* w_in   = (const float*)d_in[4];
  const float* b_in   = (const float*)d_in[5];
  const float* ws_mid = (const float*)d_in[6];
  const float* bs_mid = (const float*)d_in[7];
  const float* w_out  = (const float*)d_in[8];
  const float* b_out  = (const float*)d_in[9];
  float* xcur = (float*)d_out;

  char* bws = (char*)d_ws;
  size_t off = 0;
  auto carve = [&](size_t bytes) { char* pp = bws + off; off += (bytes + 255) & ~(size_t)255; return (void*)pp; };
  __hip_bfloat16* actA = (__hip_bfloat16*)carve((size_t)BB*PP*64*2);
  __hip_bfloat16* actB = (__hip_bfloat16*)carve((size_t)BB*PP*64*2);
  unsigned* t    = (unsigned*)carve((size_t)BB*CC*HW*4);   // packed fp16 pairs
  unsigned* csmh = (unsigned*)carve((size_t)BB*CC*HW*4);   // packed fp16 csm
  cf* rbuf0 = (cf*)carve((size_t)BB*HW*8);
  cf* rbuf1 = (cf*)carve((size_t)BB*HW*8);
  cf* pbuf0 = (cf*)carve((size_t)BB*HW*8);
  cf* pbuf1 = (cf*)carve((size_t)BB*HW*8);
  cf* xc    = (cf*)carve((size_t)BB*HW*8);
  cf* Ap    = (cf*)carve((size_t)BB*HW*8);
  float* sc = (float*)carve(4096);
  __hip_bfloat16* wrep = (__hip_bfloat16*)carve((size_t)7*9*64*64*2);

  hipMemcpyAsync(xcur, under, (size_t)BB*2*HW*sizeof(float), hipMemcpyDeviceToDevice, stream);

  zero_sc_k<<<1, 256, 0, stream>>>(sc);
  repack_mid_k<<<(7*9*64*64 + 255)/256, 256, 0, stream>>>(ws_mid, wrep);
  repack_csm_k<<<(BB*CC*HW + 255)/256, 256, 0, stream>>>(csm, csmh);
  zero_guard_k<<<(2*BB*1540*8 + 255)/256, 256, 0, stream>>>(actA, actB);

  dim3 cgrid(WW/32, HH/8, BB);       // conv_in / conv_mid / conv_out (32x8 tiles)
  dim3 agrid(HH/4, CC, BB);
  dim3 bgrid(WW/8, CC, BB);
  dim3 c2grid(HH, BB);               // pass_c: one row per block
  const int egrid  = BB*HW/256;
  const int egrid2 = BB*HW/512;      // update_k: 2 cf per thread

  __hip_bfloat16* bufs[2] = { actA, actB };
  cf* rb[2] = { rbuf0, rbuf1 };
  cf* pb[2] = { pbuf0, pbuf1 };

  for (int layer = 0; layer < NLAYERS; ++layer) {
    float* scL = sc + layer*128;
    conv_in_k<<<cgrid, 256, 0, stream>>>(xcur, w_in, b_in, bufs[0]);
    for (int i = 0; i < 7; ++i) {
      conv_mid_mfma_k<<<cgrid, 256, 0, stream>>>(bufs[i & 1], wrep + (size_t)i*9*4096,
                                                 bs_mid + i*64, bufs[(i + 1) & 1], (i % 2 == 0) ? 1 : 0);
    }
    conv_out_k<<<cgrid, 256, 0, stream>>>(bufs[1], w_out, b_out, xcur, under, lam,
                                          rbuf0, pbuf0, xc, scL);
    for (int it = 0; it < CGITERS; ++it) {
      cf* rold = rb[(it + 1) & 1];
      cf* rnew = rb[it & 1];
      cf* pold = pb[(it + 1) & 1];
      cf* pnew = pb[it & 1];
      if (it == 0) { rold = rbuf0; pold = pbuf0; rnew = rbuf0; pnew = pbuf0; }
      if (it > 0)
        update_k<<<egrid2, 256, 0, stream>>>((const float4*)rold, (float4*)rnew,
                                             (const float4*)pold, (float4*)pnew,
                                             (float4*)xc, (const float4*)Ap, scL, it);
      pass_a_k<<<agrid, 256, 0, stream>>>(pnew, csmh, t);
      pass_b_k<<<bgrid, 256, 0, stream>>>(t, mask);
      pass_c_k<<<c2grid, 256, 0, stream>>>(t, csmh, pnew, Ap, lam, scL, it);
    }
    final_x_k<<<egrid, 256, 0, stream>>>(xc, pb[(CGITERS - 1) & 1], scL, xcur);
  }
}